// Round 11
// baseline (487.252 us; speedup 1.0000x reference)
//
#include <hip/hip_runtime.h>
#include <math.h>

#define D 66
#define SP 68                 // padded fp32 row stride, 16B-aligned rows, cols 66,67 always 0
#define NEG_SLOPE 0.2f
#define CAP 6144

typedef short s8v __attribute__((ext_vector_type(8)));   // 8 bf16 bit-patterns = 4 VGPRs
typedef float f4v __attribute__((ext_vector_type(4)));

__device__ __forceinline__ float lrelu(float a){ return a > 0.f ? a : NEG_SLOPE * a; }
__device__ __forceinline__ void fma4(float4& a, float s, const float4& w){
  a.x = fmaf(s, w.x, a.x); a.y = fmaf(s, w.y, a.y);
  a.z = fmaf(s, w.z, a.z); a.w = fmaf(s, w.w, a.w);
}
__device__ __forceinline__ unsigned short bf16r(float f){   // RNE f32->bf16 (pack-time only)
  unsigned u = __float_as_uint(f);
  u += 0x7FFFu + ((u >> 16) & 1u);
  return (unsigned short)(u >> 16);
}
__device__ __forceinline__ float bf16f(unsigned short b){
  return __uint_as_float(((unsigned)b) << 16);
}
// truncation 3-term split: v = a0 + a1 + a2 + r, |r| <= 2^-24 |v|; each step EXACT
__device__ __forceinline__ void split8t(const float* p, s8v& a0, s8v& a1, s8v& a2){
  #pragma unroll
  for (int j = 0; j < 8; j++){
    float v = p[j];
    unsigned u0 = __float_as_uint(v) & 0xFFFF0000u;
    float r1 = v - __uint_as_float(u0);
    unsigned u1 = __float_as_uint(r1) & 0xFFFF0000u;
    float r2 = r1 - __uint_as_float(u1);
    unsigned u2 = __float_as_uint(r2);
    a0[j] = (short)(u0 >> 16);
    a1[j] = (short)(u1 >> 16);
    a2[j] = (short)(u2 >> 16);
  }
}
#define MM6(acc, a0, a1, a2, b0v, b1v, b2v)                                \
  acc = __builtin_amdgcn_mfma_f32_16x16x32_bf16(a0, b0v, acc, 0, 0, 0);    \
  acc = __builtin_amdgcn_mfma_f32_16x16x32_bf16(a1, b0v, acc, 0, 0, 0);    \
  acc = __builtin_amdgcn_mfma_f32_16x16x32_bf16(a0, b1v, acc, 0, 0, 0);    \
  acc = __builtin_amdgcn_mfma_f32_16x16x32_bf16(a2, b0v, acc, 0, 0, 0);    \
  acc = __builtin_amdgcn_mfma_f32_16x16x32_bf16(a1, b1v, acc, 0, 0, 0);    \
  acc = __builtin_amdgcn_mfma_f32_16x16x32_bf16(a0, b2v, acc, 0, 0, 0);

// ---------------- BN stats + bucket hist (merged) ----------------
__global__ __launch_bounds__(256) void k_stats_hist(const float* __restrict__ h, const int* __restrict__ dst,
                                                    float* __restrict__ sums, int* __restrict__ bhist,
                                                    int n, int E){
  int t = threadIdx.x;
  if (blockIdx.x < 256){
    __shared__ float ls[2 * D];
    if (t < 2 * D) ls[t] = 0.f;
    __syncthreads();
    int rpb = (n + 255) / 256;
    int r0 = blockIdx.x * rpb;
    int r1 = min(n, r0 + rpb);
    if (t < 3 * D){
      int c = t % D, seg = t / D;
      float s1 = 0.f, s2 = 0.f;
      for (int r = r0 + seg; r < r1; r += 3){
        float v = h[(size_t)r * D + c];
        s1 += v; s2 += v * v;
      }
      atomicAdd(&ls[c], s1);
      atomicAdd(&ls[D + c], s2);
    }
    __syncthreads();
    if (t < 2 * D) atomicAdd(&sums[t], ls[t]);
  } else {
    __shared__ int hh[256];
    hh[t] = 0;
    __syncthreads();
    int stride = 256 * 256;
    for (int e = (blockIdx.x - 256) * 256 + t; e < E; e += stride)
      atomicAdd(&hh[dst[e] >> 8], 1);
    __syncthreads();
    if (hh[t]) atomicAdd(&bhist[t], hh[t]);
  }
}

// ---------------- merged prep: BN finalize + GAT pack + FC pack ----------------
struct PrepArgs {
  const float *sums, *gamma, *beta;
  const float *We[3], *ae[3];
  const float *gw[3];
  const float *fw[5], *fb[5];
  float *misc; short *W0, *W1, *W2; short *F0, *F1, *F2; float *bpack;
  int n;
};

__global__ __launch_bounds__(256) void k_prep(PrepArgs pa){
  int t = threadIdx.x;
  if (blockIdx.x == 0){
    if (t < D){
      float mean = pa.sums[t] / (float)pa.n;
      float var  = pa.sums[D + t] / (float)pa.n - mean * mean;
      float inv  = rsqrtf(var + 1e-5f);
      float sc = pa.gamma[t] * inv;
      pa.misc[t] = sc;
      pa.misc[D + t] = pa.beta[t] - mean * sc;
    } else if (t >= D && t < D + 3){
      int l = t - D;
      float c = 0.f;
      for (int d = 0; d < D; d++) c += pa.We[l][d] * pa.ae[l][d];
      pa.misc[2 * D + l] = c;
    }
  } else if (blockIdx.x <= 12){
    int tid = (blockIdx.x - 1) * 256 + t;
    if (tid >= 3 * 960) return;
    int L = tid & 63;
    int ct = (tid >> 6) % 15;
    int lay = tid / 960;
    const float* w = pa.gw[lay];
    int c = ct / 5, tt = ct % 5;
    int nn = tt * 16 + (L & 15);
    int kb = c * 32 + (L >> 4) * 8;
    #pragma unroll
    for (int j = 0; j < 8; j++){
      int k = kb + j;
      float v = (k < D && nn < D) ? w[k * D + nn] : 0.f;
      unsigned short b0 = bf16r(v);  float f0 = bf16f(b0);
      float r1 = v - f0;
      unsigned short b1 = bf16r(r1); float f1 = bf16f(b1);
      unsigned short b2 = bf16r(r1 - f1);
      pa.W0[tid * 8 + j] = (short)b0;
      pa.W1[tid * 8 + j] = (short)b1;
      pa.W2[tid * 8 + j] = (short)b2;
    }
  } else {
    int tid = (blockIdx.x - 13) * 256 + t;
    if (tid < 5 * 960){
      int L = tid & 63;
      int ct = (tid >> 6) % 15;
      int lay = tid / 960;
      const float* w = pa.fw[lay];
      int ncol = (lay == 4) ? 22 : D;
      int c = ct / 5, tt = ct % 5;
      int nn = tt * 16 + (L & 15);
      int kb = c * 32 + (L >> 4) * 8;
      #pragma unroll
      for (int j = 0; j < 8; j++){
        int k = kb + j;
        float v = (k < D && nn < ncol) ? w[k * ncol + nn] : 0.f;
        unsigned short b0 = bf16r(v);  float f0 = bf16f(b0);
        float r1 = v - f0;
        unsigned short b1 = bf16r(r1); float f1 = bf16f(b1);
        unsigned short b2 = bf16r(r1 - f1);
        pa.F0[tid * 8 + j] = (short)b0;
        pa.F1[tid * 8 + j] = (short)b1;
        pa.F2[tid * 8 + j] = (short)b2;
      }
    } else if (tid < 5 * 960 + 400){
      int i = tid - 5 * 960;
      int lay = i / 80, col = i % 80;
      int ncol = (lay == 4) ? 22 : D;
      pa.bpack[i] = (col < ncol) ? pa.fb[lay][col] : 0.f;
    }
  }
}

// ---------------- CSR build: binned counting sort ----------------
__global__ void k_bscan(const int* __restrict__ bhist, int* __restrict__ bbase,
                        int* __restrict__ gcur, int* __restrict__ rowptr, int N, int E){
  __shared__ int sh[256];
  int t = threadIdx.x;
  int v = bhist[t];
  sh[t] = v; __syncthreads();
  for (int o = 1; o < 256; o <<= 1){
    int u = (t >= o) ? sh[t - o] : 0;
    __syncthreads();
    sh[t] += u;
    __syncthreads();
  }
  int ex = sh[t] - v;
  bbase[t] = ex;
  gcur[t] = ex;
  if (t == 255){ bbase[256] = sh[255]; rowptr[N] = E; }
}

#define PCHUNK 4096
__global__ __launch_bounds__(256) void k_part(const int* __restrict__ src, const int* __restrict__ dst,
                                              const float* __restrict__ ew,
                                              int* __restrict__ gcur, int2* __restrict__ tmp, int E){
  __shared__ int hist[256];
  __shared__ int base[256];
  int t = threadIdx.x;
  int e0 = blockIdx.x * PCHUNK;
  int eend = min(E, e0 + PCHUNK);
  hist[t] = 0;
  __syncthreads();
  for (int e = e0 + t; e < eend; e += 256)
    atomicAdd(&hist[dst[e] >> 8], 1);
  __syncthreads();
  if (hist[t] > 0) base[t] = atomicAdd(&gcur[t], hist[t]);
  hist[t] = 0;
  __syncthreads();
  for (int e = e0 + t; e < eend; e += 256){
    int d = dst[e];
    int b = d >> 8;
    int off = atomicAdd(&hist[b], 1);
    tmp[base[b] + off] = make_int2((src[e] & 0xffff) | ((d & 255) << 16), __float_as_int(ew[e]));
  }
}

__global__ __launch_bounds__(256) void k_bsort(const int2* __restrict__ tmp, const int* __restrict__ bbase,
                                               int2* __restrict__ epair, int* __restrict__ rowptr, int N){
  __shared__ int2 ebuf[CAP];
  __shared__ int lcnt[256];
  __shared__ int sc[256];
  __shared__ int lcur[256];
  int b = blockIdx.x, t = threadIdx.x;
  int s0 = bbase[b], s1 = bbase[b + 1];
  int cnt = s1 - s0;
  lcnt[t] = 0;
  __syncthreads();
  for (int j = t; j < cnt; j += 256){
    int2 e = tmp[s0 + j];
    if (j < CAP) ebuf[j] = e;
    atomicAdd(&lcnt[(e.x >> 16) & 255], 1);
  }
  __syncthreads();
  int v = lcnt[t];
  sc[t] = v; __syncthreads();
  for (int o = 1; o < 256; o <<= 1){
    int u = (t >= o) ? sc[t - o] : 0;
    __syncthreads();
    sc[t] += u;
    __syncthreads();
  }
  int ex = sc[t] - v;
  int node = (b << 8) + t;
  if (node < N) rowptr[node] = s0 + ex;
  lcur[t] = ex;
  __syncthreads();
  for (int j = t; j < cnt; j += 256){
    int2 e = (j < CAP) ? ebuf[j] : tmp[s0 + j];
    int i = (e.x >> 16) & 255;
    int p = atomicAdd(&lcur[i], 1);
    epair[s0 + p] = make_int2(e.x & 0xffff, e.y);
  }
}

// ---------------- GAT GEMM via 3-term bf16 MFMA; optional fused BN on input ----------------
template<bool BN_IN>
__global__ __launch_bounds__(256) void k_mm(const float* __restrict__ X,
    const short* __restrict__ W0, const short* __restrict__ W1, const short* __restrict__ W2,
    const float* __restrict__ att_s, const float* __restrict__ att_d,
    const float* __restrict__ bn,
    float* __restrict__ Y, float* __restrict__ a_src, float* __restrict__ a_dst, int n){
  const int wv = threadIdx.x >> 6, L = threadIdx.x & 63;
  const int quad = L >> 4, m = L & 15;
  const int row0 = blockIdx.x * 64 + wv * 16;
  const int lrow = min(row0 + m, n - 1);
  f4v acc[5];
  #pragma unroll
  for (int t = 0; t < 5; t++) acc[t] = (f4v){0.f,0.f,0.f,0.f};

  #pragma unroll
  for (int c = 0; c < 3; c++){
    float xv[8];
    if (c < 2){
      if (BN_IN){
        const float* hr = X + (size_t)lrow * D + c * 32 + quad * 8;
        #pragma unroll
        for (int j = 0; j < 8; j += 2){
          float2 hv = *(const float2*)(hr + j);
          int col = c * 32 + quad * 8 + j;
          xv[j]     = hv.x * bn[col]     + bn[D + col];
          xv[j + 1] = hv.y * bn[col + 1] + bn[D + col + 1];
        }
      } else {
        const float* xr = X + (size_t)lrow * SP;
        float4 p0 = *(const float4*)&xr[c * 32 + quad * 8];
        float4 p1 = *(const float4*)&xr[c * 32 + quad * 8 + 4];
        xv[0] = p0.x; xv[1] = p0.y; xv[2] = p0.z; xv[3] = p0.w;
        xv[4] = p1.x; xv[5] = p1.y; xv[6] = p1.z; xv[7] = p1.w;
      }
    } else {
      #pragma unroll
      for (int j = 0; j < 8; j++) xv[j] = 0.f;
      if (quad == 0){
        if (BN_IN){
          float2 hv = *(const float2*)(X + (size_t)lrow * D + 64);
          xv[0] = hv.x * bn[64] + bn[D + 64];
          xv[1] = hv.y * bn[65] + bn[D + 65];
        } else {
          float4 p0 = *(const float4*)&X[(size_t)lrow * SP + 64];
          xv[0] = p0.x; xv[1] = p0.y; xv[2] = p0.z; xv[3] = p0.w;
        }
      }
    }
    s8v a0, a1, a2;
    split8t(xv, a0, a1, a2);
    const short* b0p = W0 + (c * 5) * 512 + L * 8;
    const short* b1p = W1 + (c * 5) * 512 + L * 8;
    const short* b2p = W2 + (c * 5) * 512 + L * 8;
    #pragma unroll
    for (int t = 0; t < 5; t++){
      s8v b0v = *(const s8v*)(b0p + t * 512);
      s8v b1v = *(const s8v*)(b1p + t * 512);
      s8v b2v = *(const s8v*)(b2p + t * 512);
      MM6(acc[t], a0, a1, a2, b0v, b1v, b2v)
    }
  }

  float ps[4] = {0.f,0.f,0.f,0.f}, pd[4] = {0.f,0.f,0.f,0.f};
  #pragma unroll
  for (int t = 0; t < 5; t++){
    int col = t * 16 + m;
    float as_v = 0.f, ad_v = 0.f;
    if (col < D){ as_v = att_s[col]; ad_v = att_d[col]; }
    #pragma unroll
    for (int r = 0; r < 4; r++){
      ps[r] += acc[t][r] * as_v;
      pd[r] += acc[t][r] * ad_v;
    }
  }
  #pragma unroll
  for (int r = 0; r < 4; r++){
    int rw = row0 + quad * 4 + r;
    if (rw < n){
      float* yr = Y + (size_t)rw * SP;
      #pragma unroll
      for (int t = 0; t < 4; t++) yr[t * 16 + m] = acc[t][r];
      if (m < 4) yr[64 + m] = (m < 2) ? acc[4][r] : 0.f;
    }
  }
  #pragma unroll
  for (int o = 1; o <= 8; o <<= 1){
    #pragma unroll
    for (int r = 0; r < 4; r++){
      ps[r] += __shfl_xor(ps[r], o);
      pd[r] += __shfl_xor(pd[r], o);
    }
  }
  if (m == 0){
    #pragma unroll
    for (int r = 0; r < 4; r++){
      int rw = row0 + quad * 4 + r;
      if (rw < n){ a_src[rw] = ps[r]; a_dst[rw] = pd[r]; }
    }
  }
}

// ---------------- Fused 5-layer FC head: 32-row blocks, t-split across wave pairs ----------------
// Waves (2k,2k+1) share rows rg=k via LDS: wave A computes col-tiles t 0..2, wave B t 3..4.
// Grid doubles vs 64-row version -> ~24 waves/CU; per-wave MFMA chain ~halves.
#define FST 84
__global__ __launch_bounds__(256) void k_fcmm(const float* __restrict__ X,
    const short* __restrict__ W0, const short* __restrict__ W1, const short* __restrict__ W2,
    const float* __restrict__ bpack, float* __restrict__ out, int n){
  __shared__ __align__(16) float xs[2][16][FST];
  const int wv = threadIdx.x >> 6, L = threadIdx.x & 63;
  const int quad = L >> 4, m = L & 15;
  const int rg = wv >> 1, th = wv & 1;
  const int row0 = blockIdx.x * 32 + rg * 16;
  const int lrow = min(row0 + m, n - 1);
  const float* xr = X + (size_t)lrow * SP;

  for (int l = 0; l < 5; l++){
    const int t0 = (l == 4) ? th : (th ? 3 : 0);
    const int nt = (l == 4) ? 1  : (th ? 2 : 3);
    f4v acc[3];
    #pragma unroll
    for (int t = 0; t < 3; t++) acc[t] = (f4v){0.f,0.f,0.f,0.f};
    #pragma unroll
    for (int c = 0; c < 3; c++){
      float xv[8];
      if (l == 0){
        if (c < 2){
          float4 p0 = *(const float4*)&xr[c * 32 + quad * 8];
          float4 p1 = *(const float4*)&xr[c * 32 + quad * 8 + 4];
          xv[0] = p0.x; xv[1] = p0.y; xv[2] = p0.z; xv[3] = p0.w;
          xv[4] = p1.x; xv[5] = p1.y; xv[6] = p1.z; xv[7] = p1.w;
        } else {
          float4 p0 = make_float4(0.f, 0.f, 0.f, 0.f);
          if (quad == 0) p0 = *(const float4*)&xr[64];
          xv[0] = p0.x; xv[1] = p0.y; xv[2] = p0.z; xv[3] = p0.w;
          xv[4] = 0.f; xv[5] = 0.f; xv[6] = 0.f; xv[7] = 0.f;
        }
      } else {
        if (c == 2 && quad >= 2){
          #pragma unroll
          for (int j = 0; j < 8; j++) xv[j] = 0.f;
        } else {
          float4 p0 = *(const float4*)&xs[rg][m][c * 32 + quad * 8];
          float4 p1 = *(const float4*)&xs[rg][m][c * 32 + quad * 8 + 4];
          xv[0] = p0.x; xv[1] = p0.y; xv[2] = p0.z; xv[3] = p0.w;
          xv[4] = p1.x; xv[5] = p1.y; xv[6] = p1.z; xv[7] = p1.w;
        }
      }
      s8v a0, a1, a2;
      split8t(xv, a0, a1, a2);
      const short* b0p = W0 + ((l * 3 + c) * 5 + t0) * 512 + L * 8;
      const short* b1p = W1 + ((l * 3 + c) * 5 + t0) * 512 + L * 8;
      const short* b2p = W2 + ((l * 3 + c) * 5 + t0) * 512 + L * 8;
      for (int t = 0; t < nt; t++){
        s8v b0v = *(const s8v*)(b0p + t * 512);
        s8v b1v = *(const s8v*)(b1p + t * 512);
        s8v b2v = *(const s8v*)(b2p + t * 512);
        MM6(acc[t], a0, a1, a2, b0v, b1v, b2v)
      }
    }
    if (l < 4){
      __syncthreads();   // prior layer's xs reads done block-wide before overwrite
      for (int t = 0; t < nt; t++){
        int col = (t0 + t) * 16 + m;
        float bv = bpack[l * 80 + col];   // padded cols: acc=0, bv=0 -> relu(0)=0
        #pragma unroll
        for (int r = 0; r < 4; r++){
          float v = acc[t][r] + bv;
          xs[rg][quad * 4 + r][col] = v > 0.f ? v : 0.f;
        }
      }
      __syncthreads();   // writes visible before next layer's reads
    } else {
      int col = t0 * 16 + m;
      #pragma unroll
      for (int r = 0; r < 4; r++){
        int rw = row0 + quad * 4 + r;
        if (col < 22 && rw < n) out[(size_t)rw * 22 + col] = acc[0][r] + bpack[4 * 80 + col];
      }
    }
  }
}

// ---------------- GAT softmax + aggregate: one wave per dst node, 16 edges/iter ----------------
// Pass C uses direct broadcast reads per 4-lane group (no __shfl in the hot loop);
// all remaining __shfl_xor reductions run with every lane active.
__global__ __launch_bounds__(256) void k_agg(const float* __restrict__ y,
                                             const float* __restrict__ a_src, const float* __restrict__ a_dst,
                                             const int* __restrict__ rowptr, const int2* __restrict__ epair,
                                             const float* __restrict__ misc, int cidx,
                                             const float* __restrict__ bias,
                                             float* __restrict__ xout, int n){
  const int wid  = (int)((blockIdx.x * (size_t)blockDim.x + threadIdx.x) >> 6);
  const int lane = threadIdx.x & 63;
  if (wid >= n) return;
  const int beg = rowptr[wid];
  const int deg = rowptr[wid + 1] - beg;
  const float ce  = misc[2 * D + cidx];
  const float adn = a_dst[wid];

  // phase 1: softmax max & denom (wave-uniform)
  float mx, inv;
  if (deg <= 64){
    float al = -INFINITY;
    if (lane < deg){
      int2 ep = epair[beg + lane];
      al = lrelu(a_src[ep.x] + adn + ce * __int_as_float(ep.y));
    }
    mx = al;
    #pragma unroll
    for (int o = 32; o; o >>= 1) mx = fmaxf(mx, __shfl_xor(mx, o));
    float ex = (lane < deg) ? __expf(al - mx) : 0.f;
    float sum = ex;
    #pragma unroll
    for (int o = 32; o; o >>= 1) sum += __shfl_xor(sum, o);
    inv = 1.f / (sum + 1e-16f);
  } else {
    mx = -INFINITY;
    for (int j0 = 0; j0 < deg; j0 += 64){
      int j = j0 + lane;
      if (j < deg){
        int2 ep = epair[beg + j];
        mx = fmaxf(mx, lrelu(a_src[ep.x] + adn + ce * __int_as_float(ep.y)));
      }
    }
    #pragma unroll
    for (int o = 32; o; o >>= 1) mx = fmaxf(mx, __shfl_xor(mx, o));
    float sum = 0.f;
    for (int j0 = 0; j0 < deg; j0 += 64){
      int j = j0 + lane;
      if (j < deg){
        int2 ep = epair[beg + j];
        sum += __expf(lrelu(a_src[ep.x] + adn + ce * __int_as_float(ep.y)) - mx);
      }
    }
    #pragma unroll
    for (int o = 32; o; o >>= 1) sum += __shfl_xor(sum, o);
    inv = 1.f / (sum + 1e-16f);
  }

  // phase 2: gather-accumulate, 4 lanes per edge, 16 edges in flight
  const int g = lane >> 2, q = lane & 3;
  float4 acc0 = make_float4(0.f,0.f,0.f,0.f);
  float4 acc1 = make_float4(0.f,0.f,0.f,0.f);
  float4 acc2 = make_float4(0.f,0.f,0.f,0.f);
  float4 acc3 = make_float4(0.f,0.f,0.f,0.f);
  float2 tacc = make_float2(0.f,0.f);
  for (int e0 = 0; e0 < deg; e0 += 16){
    int e = e0 + g;
    if (e < deg){
      int2 ep = epair[beg + e];                     // 4-lane broadcast
      float co = __expf(lrelu(a_src[ep.x] + adn + ce * __int_as_float(ep.y)) - mx) * inv;
      const float* row = y + (size_t)ep.x * SP;
      fma4(acc0, co, *(const float4*)&row[      4 * q]);
      fma4(acc1, co, *(const float4*)&row[16 + 4 * q]);
      fma4(acc2, co, *(const float4*)&row[32 + 4 * q]);
      fma4(acc3, co, *(const float4*)&row[48 + 4 * q]);
      if (q == 0){
        float2 tv = *(const float2*)&row[64];
        tacc.x += co * tv.x; tacc.y += co * tv.y;
      }
    }
  }

  // reduce across the 16 edge-groups (lane bits 2..5)
  #pragma unroll
  for (int o = 4; o <= 32; o <<= 1){
    acc0.x += __shfl_xor(acc0.x, o); acc0.y += __shfl_xor(acc0.y, o);
    acc0.z += __shfl_xor(acc0.z, o); acc0.w += __shfl_xor(acc0.w, o);
    acc1.x += __shfl_xor(acc1.x, o); acc1.y += __shfl_xor(acc1.y, o);
    acc1.z += __shfl_xor(acc1.z, o); acc1.w += __shfl_xor(acc1.w, o);
    acc2.x += __shfl_xor(acc2.x, o); acc2.y += __shfl_xor(acc2.y, o);
    acc2.z += __shfl_xor(acc2.z, o); acc2.w += __shfl_xor(acc2.w, o);
    acc3.x += __shfl_xor(acc3.x, o); acc3.y += __shfl_xor(acc3.y, o);
    acc3.z += __shfl_xor(acc3.z, o); acc3.w += __shfl_xor(acc3.w, o);
    tacc.x += __shfl_xor(tacc.x, o); tacc.y += __shfl_xor(tacc.y, o);
  }

  float* orow = xout + (size_t)wid * SP;
  if (lane < 4){
    int c0 = 4 * lane;
    float4 v;
    v.x = acc0.x + bias[c0+0]; v.x = v.x > 0.f ? v.x : 0.f;
    v.y = acc0.y + bias[c0+1]; v.y = v.y > 0.f ? v.y : 0.f;
    v.z = acc0.z + bias[c0+2]; v.z = v.z > 0.f ? v.z : 0.f;
    v.w = acc0.w + bias[c0+3]; v.w = v.w > 0.f ? v.w : 0.f;
    *(float4*)&orow[c0] = v;
    v.x = acc1.x + bias[16+c0+0]; v.x = v.x > 0.f ? v.x : 0.f;
    v.y = acc1.y + bias[16+c0+1]; v.y = v.y > 0.f ? v.y : 0.f;
    v.z = acc1.z + bias[16+c0+2]; v.z = v.z > 0.f ? v.z : 0.f;
    v.w = acc1.w + bias[16+c0+3]; v.w = v.w > 0.f ? v.w : 0.f;
    *(float4*)&orow[16 + c0] = v;
    v.x = acc2.x + bias[32+c0+0]; v.x = v.x > 0.f ? v.x : 0.f;
    v.y = acc2.y + bias[32+c0+1]; v.y = v.y > 0.f ? v.y : 0.f;
    v.z = acc2.z + bias[32+c0+2]; v.z = v.z > 0.f ? v.z : 0.f;
    v.w = acc2.w + bias[32+c0+3]; v.w = v.w > 0.f ? v.w : 0.f;
    *(float4*)&orow[32 + c0] = v;
    v.x = acc3.x + bias[48+c0+0]; v.x = v.x > 0.f ? v.x : 0.f;
    v.y = acc3.y + bias[48+c0+1]; v.y = v.y > 0.f ? v.y : 0.f;
    v.z = acc3.z + bias[48+c0+2]; v.z = v.z > 0.f ? v.z : 0.f;
    v.w = acc3.w + bias[48+c0+3]; v.w = v.w > 0.f ? v.w : 0.f;
    *(float4*)&orow[48 + c0] = v;
  }
  if (lane == 0){
    float4 tv;
    tv.x = tacc.x + bias[64]; tv.x = tv.x > 0.f ? tv.x : 0.f;
    tv.y = tacc.y + bias[65]; tv.y = tv.y > 0.f ? tv.y : 0.f;
    tv.z = 0.f; tv.w = 0.f;
    *(float4*)&orow[64] = tv;
  }
}

// ---------------- launch ----------------
extern "C" void kernel_launch(void* const* d_in, const int* in_sizes, int n_in,
                              void* d_out, int out_size, void* d_ws, size_t ws_size,
                              hipStream_t stream){
  const float* h     = (const float*)d_in[0];
  const int*   ei    = (const int*)  d_in[1];
  const float* ew    = (const float*)d_in[2];
  const float* gamma = (const float*)d_in[3];
  const float* beta  = (const float*)d_in[4];
  const float *Wl[3], *bl[3], *asl[3], *adl[3], *Wel[3], *ael[3];
  int idx = 5;
  for (int l = 0; l < 3; l++){
    Wl[l]  = (const float*)d_in[idx++];
    bl[l]  = (const float*)d_in[idx++];
    asl[l] = (const float*)d_in[idx++];
    adl[l] = (const float*)d_in[idx++];
    Wel[l] = (const float*)d_in[idx++];
    ael[l] = (const float*)d_in[idx++];
  }
  const float *fw[5], *fb[5];
  for (int l = 0; l < 5; l++){ fw[l] = (const float*)d_in[idx++]; fb[l] = (const float*)d_in[idx++]; }

  int N = in_sizes[0] / D;
  int E = in_sizes[1] / 2;
  const int* src  = ei;
  const int* dstp = ei + E;

  char* base = (char*)d_ws;
  size_t o = 0;
  auto alloc = [&](size_t b){ size_t r = o; o += (b + 255) & ~(size_t)255; return r; };
  float*  bufA   = (float*)(base + alloc((size_t)N * SP * 4));
  float*  bufB   = (float*)(base + alloc((size_t)N * SP * 4));
  float*  a_src  = (float*)(base + alloc((size_t)N * 4));
  float*  a_dst  = (float*)(base + alloc((size_t)N * 4));
  float*  misc   = (float*)(base + alloc(512 * 4));
  float*  sums   = (float*)(base + alloc(2 * D * 4));
  int*    rowptr = (int*)  (base + alloc((size_t)(N + 1) * 4));
  int*    bhist  = (int*)  (base + alloc(256 * 4));
  int*    bbase  = (int*)  (base + alloc(257 * 4));
  int*    gcur   = (int*)  (base + alloc(256 * 4));
  int2*   epair  = (int2*) (base + alloc((size_t)E * 8));
  short*  W0p    = (short*)(base + alloc(3 * 7680 * 2));
  short*  W1p    = (short*)(base + alloc(3 * 7680 * 2));
  short*  W2p    = (short*)(base + alloc(3 * 7680 * 2));
  short*  FW0p   = (short*)(base + alloc(5 * 7680 * 2));
  short*  FW1p   = (short*)(base + alloc(5 * 7680 * 2));
  short*  FW2p   = (short*)(base + alloc(5 * 7680 * 2));
  float*  bpack  = (float*)(base + alloc(400 * 4));
  int2*   tmp    = (int2*)bufB;   // alias: bufB unused until first k_mm

  hipMemsetAsync(sums, 0, 2 * D * 4, stream);
  hipMemsetAsync(bhist, 0, 256 * 4, stream);

  k_stats_hist<<<512, 256, 0, stream>>>(h, dstp, sums, bhist, N, E);

  PrepArgs pa;
  pa.sums = sums; pa.gamma = gamma; pa.beta = beta;
  for (int l = 0; l < 3; l++){ pa.We[l] = Wel[l]; pa.ae[l] = ael[l]; pa.gw[l] = Wl[l]; }
  for (int l = 0; l < 5; l++){ pa.fw[l] = fw[l]; pa.fb[l] = fb[l]; }
  pa.misc = misc; pa.W0 = W0p; pa.W1 = W1p; pa.W2 = W2p;
  pa.F0 = FW0p; pa.F1 = FW1p; pa.F2 = FW2p; pa.bpack = bpack; pa.n = N;
  k_prep<<<34, 256, 0, stream>>>(pa);

  int NB = (N + 255) >> 8;
  k_bscan<<<1, 256, 0, stream>>>(bhist, bbase, gcur, rowptr, N, E);
  k_part<<<(E + PCHUNK - 1) / PCHUNK, 256, 0, stream>>>(src, dstp, ew, gcur, tmp, E);
  k_bsort<<<NB, 256, 0, stream>>>(tmp, bbase, epair, rowptr, N);

  int gb = (N + 63) / 64;
  int ab = (N + 3) / 4;

  k_mm<true ><<<gb, 256, 0, stream>>>(h,    W0p + 0 * 7680, W1p + 0 * 7680, W2p + 0 * 7680,
                                      asl[0], adl[0], misc, bufB, a_src, a_dst, N);
  k_agg<<<ab, 256, 0, stream>>>(bufB, a_src, a_dst, rowptr, epair, misc, 0, bl[0], bufA, N);
  k_mm<false><<<gb, 256, 0, stream>>>(bufA, W0p + 1 * 7680, W1p + 1 * 7680, W2p + 1 * 7680,
                                      asl[1], adl[1], misc, bufB, a_src, a_dst, N);
  k_agg<<<ab, 256, 0, stream>>>(bufB, a_src, a_dst, rowptr, epair, misc, 1, bl[1], bufA, N);
  k_mm<false><<<gb, 256, 0, stream>>>(bufA, W0p + 2 * 7680, W1p + 2 * 7680, W2p + 2 * 7680,
                                      asl[2], adl[2], misc, bufB, a_src, a_dst, N);
  k_agg<<<ab, 256, 0, stream>>>(bufB, a_src, a_dst, rowptr, epair, misc, 2, bl[2], bufA, N);

  int gb2 = (N + 31) / 32;
  k_fcmm<<<gb2, 256, 0, stream>>>(bufA, FW0p, FW1p, FW2p, bpack, (float*)d_out, N);
}

// Round 12
// 440.897 us; speedup vs baseline: 1.1051x; 1.1051x over previous
//
#include <hip/hip_runtime.h>
#include <math.h>

#define D 66
#define SP 68                 // padded fp32 row stride, 16B-aligned rows, cols 66,67 always 0
#define NEG_SLOPE 0.2f
#define CAP 6144

typedef short s8v __attribute__((ext_vector_type(8)));   // 8 bf16 bit-patterns = 4 VGPRs
typedef float f4v __attribute__((ext_vector_type(4)));

__device__ __forceinline__ float lrelu(float a){ return a > 0.f ? a : NEG_SLOPE * a; }
__device__ __forceinline__ void fma4(float4& a, float s, const float4& w){
  a.x = fmaf(s, w.x, a.x); a.y = fmaf(s, w.y, a.y);
  a.z = fmaf(s, w.z, a.z); a.w = fmaf(s, w.w, a.w);
}
__device__ __forceinline__ unsigned short bf16r(float f){   // RNE f32->bf16 (pack-time only)
  unsigned u = __float_as_uint(f);
  u += 0x7FFFu + ((u >> 16) & 1u);
  return (unsigned short)(u >> 16);
}
__device__ __forceinline__ float bf16f(unsigned short b){
  return __uint_as_float(((unsigned)b) << 16);
}
// truncation 3-term split: v = a0 + a1 + a2 + r, |r| <= 2^-24 |v|; each step EXACT
__device__ __forceinline__ void split8t(const float* p, s8v& a0, s8v& a1, s8v& a2){
  #pragma unroll
  for (int j = 0; j < 8; j++){
    float v = p[j];
    unsigned u0 = __float_as_uint(v) & 0xFFFF0000u;
    float r1 = v - __uint_as_float(u0);
    unsigned u1 = __float_as_uint(r1) & 0xFFFF0000u;
    float r2 = r1 - __uint_as_float(u1);
    unsigned u2 = __float_as_uint(r2);
    a0[j] = (short)(u0 >> 16);
    a1[j] = (short)(u1 >> 16);
    a2[j] = (short)(u2 >> 16);
  }
}
#define MM6(acc, a0, a1, a2, b0v, b1v, b2v)                                \
  acc = __builtin_amdgcn_mfma_f32_16x16x32_bf16(a0, b0v, acc, 0, 0, 0);    \
  acc = __builtin_amdgcn_mfma_f32_16x16x32_bf16(a1, b0v, acc, 0, 0, 0);    \
  acc = __builtin_amdgcn_mfma_f32_16x16x32_bf16(a0, b1v, acc, 0, 0, 0);    \
  acc = __builtin_amdgcn_mfma_f32_16x16x32_bf16(a2, b0v, acc, 0, 0, 0);    \
  acc = __builtin_amdgcn_mfma_f32_16x16x32_bf16(a1, b1v, acc, 0, 0, 0);    \
  acc = __builtin_amdgcn_mfma_f32_16x16x32_bf16(a0, b2v, acc, 0, 0, 0);

// ---------------- BN stats + bucket hist (merged) ----------------
__global__ __launch_bounds__(256) void k_stats_hist(const float* __restrict__ h, const int* __restrict__ dst,
                                                    float* __restrict__ sums, int* __restrict__ bhist,
                                                    int n, int E){
  int t = threadIdx.x;
  if (blockIdx.x < 256){
    __shared__ float ls[2 * D];
    if (t < 2 * D) ls[t] = 0.f;
    __syncthreads();
    int rpb = (n + 255) / 256;
    int r0 = blockIdx.x * rpb;
    int r1 = min(n, r0 + rpb);
    if (t < 3 * D){
      int c = t % D, seg = t / D;
      float s1 = 0.f, s2 = 0.f;
      for (int r = r0 + seg; r < r1; r += 3){
        float v = h[(size_t)r * D + c];
        s1 += v; s2 += v * v;
      }
      atomicAdd(&ls[c], s1);
      atomicAdd(&ls[D + c], s2);
    }
    __syncthreads();
    if (t < 2 * D) atomicAdd(&sums[t], ls[t]);
  } else {
    __shared__ int hh[256];
    hh[t] = 0;
    __syncthreads();
    int stride = 256 * 256;
    for (int e = (blockIdx.x - 256) * 256 + t; e < E; e += stride)
      atomicAdd(&hh[dst[e] >> 8], 1);
    __syncthreads();
    if (hh[t]) atomicAdd(&bhist[t], hh[t]);
  }
}

// ---------------- merged prep: BN finalize + GAT pack + FC pack ----------------
struct PrepArgs {
  const float *sums, *gamma, *beta;
  const float *We[3], *ae[3];
  const float *gw[3];
  const float *fw[5], *fb[5];
  float *misc; short *W0, *W1, *W2; short *F0, *F1, *F2; float *bpack;
  int n;
};

__global__ __launch_bounds__(256) void k_prep(PrepArgs pa){
  int t = threadIdx.x;
  if (blockIdx.x == 0){
    if (t < D){
      float mean = pa.sums[t] / (float)pa.n;
      float var  = pa.sums[D + t] / (float)pa.n - mean * mean;
      float inv  = rsqrtf(var + 1e-5f);
      float sc = pa.gamma[t] * inv;
      pa.misc[t] = sc;
      pa.misc[D + t] = pa.beta[t] - mean * sc;
    } else if (t >= D && t < D + 3){
      int l = t - D;
      float c = 0.f;
      for (int d = 0; d < D; d++) c += pa.We[l][d] * pa.ae[l][d];
      pa.misc[2 * D + l] = c;
    }
  } else if (blockIdx.x <= 12){
    int tid = (blockIdx.x - 1) * 256 + t;
    if (tid >= 3 * 960) return;
    int L = tid & 63;
    int ct = (tid >> 6) % 15;
    int lay = tid / 960;
    const float* w = pa.gw[lay];
    int c = ct / 5, tt = ct % 5;
    int nn = tt * 16 + (L & 15);
    int kb = c * 32 + (L >> 4) * 8;
    #pragma unroll
    for (int j = 0; j < 8; j++){
      int k = kb + j;
      float v = (k < D && nn < D) ? w[k * D + nn] : 0.f;
      unsigned short b0 = bf16r(v);  float f0 = bf16f(b0);
      float r1 = v - f0;
      unsigned short b1 = bf16r(r1); float f1 = bf16f(b1);
      unsigned short b2 = bf16r(r1 - f1);
      pa.W0[tid * 8 + j] = (short)b0;
      pa.W1[tid * 8 + j] = (short)b1;
      pa.W2[tid * 8 + j] = (short)b2;
    }
  } else {
    int tid = (blockIdx.x - 13) * 256 + t;
    if (tid < 5 * 960){
      int L = tid & 63;
      int ct = (tid >> 6) % 15;
      int lay = tid / 960;
      const float* w = pa.fw[lay];
      int ncol = (lay == 4) ? 22 : D;
      int c = ct / 5, tt = ct % 5;
      int nn = tt * 16 + (L & 15);
      int kb = c * 32 + (L >> 4) * 8;
      #pragma unroll
      for (int j = 0; j < 8; j++){
        int k = kb + j;
        float v = (k < D && nn < ncol) ? w[k * ncol + nn] : 0.f;
        unsigned short b0 = bf16r(v);  float f0 = bf16f(b0);
        float r1 = v - f0;
        unsigned short b1 = bf16r(r1); float f1 = bf16f(b1);
        unsigned short b2 = bf16r(r1 - f1);
        pa.F0[tid * 8 + j] = (short)b0;
        pa.F1[tid * 8 + j] = (short)b1;
        pa.F2[tid * 8 + j] = (short)b2;
      }
    } else if (tid < 5 * 960 + 400){
      int i = tid - 5 * 960;
      int lay = i / 80, col = i % 80;
      int ncol = (lay == 4) ? 22 : D;
      pa.bpack[i] = (col < ncol) ? pa.fb[lay][col] : 0.f;
    }
  }
}

// ---------------- CSR build: binned counting sort ----------------
__global__ void k_bscan(const int* __restrict__ bhist, int* __restrict__ bbase,
                        int* __restrict__ gcur, int* __restrict__ rowptr, int N, int E){
  __shared__ int sh[256];
  int t = threadIdx.x;
  int v = bhist[t];
  sh[t] = v; __syncthreads();
  for (int o = 1; o < 256; o <<= 1){
    int u = (t >= o) ? sh[t - o] : 0;
    __syncthreads();
    sh[t] += u;
    __syncthreads();
  }
  int ex = sh[t] - v;
  bbase[t] = ex;
  gcur[t] = ex;
  if (t == 255){ bbase[256] = sh[255]; rowptr[N] = E; }
}

#define PCHUNK 4096
__global__ __launch_bounds__(256) void k_part(const int* __restrict__ src, const int* __restrict__ dst,
                                              const float* __restrict__ ew,
                                              int* __restrict__ gcur, int2* __restrict__ tmp, int E){
  __shared__ int hist[256];
  __shared__ int base[256];
  int t = threadIdx.x;
  int e0 = blockIdx.x * PCHUNK;
  int eend = min(E, e0 + PCHUNK);
  hist[t] = 0;
  __syncthreads();
  for (int e = e0 + t; e < eend; e += 256)
    atomicAdd(&hist[dst[e] >> 8], 1);
  __syncthreads();
  if (hist[t] > 0) base[t] = atomicAdd(&gcur[t], hist[t]);
  hist[t] = 0;
  __syncthreads();
  for (int e = e0 + t; e < eend; e += 256){
    int d = dst[e];
    int b = d >> 8;
    int off = atomicAdd(&hist[b], 1);
    tmp[base[b] + off] = make_int2((src[e] & 0xffff) | ((d & 255) << 16), __float_as_int(ew[e]));
  }
}

__global__ __launch_bounds__(256) void k_bsort(const int2* __restrict__ tmp, const int* __restrict__ bbase,
                                               int2* __restrict__ epair, int* __restrict__ rowptr, int N){
  __shared__ int2 ebuf[CAP];
  __shared__ int lcnt[256];
  __shared__ int sc[256];
  __shared__ int lcur[256];
  int b = blockIdx.x, t = threadIdx.x;
  int s0 = bbase[b], s1 = bbase[b + 1];
  int cnt = s1 - s0;
  lcnt[t] = 0;
  __syncthreads();
  for (int j = t; j < cnt; j += 256){
    int2 e = tmp[s0 + j];
    if (j < CAP) ebuf[j] = e;
    atomicAdd(&lcnt[(e.x >> 16) & 255], 1);
  }
  __syncthreads();
  int v = lcnt[t];
  sc[t] = v; __syncthreads();
  for (int o = 1; o < 256; o <<= 1){
    int u = (t >= o) ? sc[t - o] : 0;
    __syncthreads();
    sc[t] += u;
    __syncthreads();
  }
  int ex = sc[t] - v;
  int node = (b << 8) + t;
  if (node < N) rowptr[node] = s0 + ex;
  lcur[t] = ex;
  __syncthreads();
  for (int j = t; j < cnt; j += 256){
    int2 e = (j < CAP) ? ebuf[j] : tmp[s0 + j];
    int i = (e.x >> 16) & 255;
    int p = atomicAdd(&lcur[i], 1);
    epair[s0 + p] = make_int2(e.x & 0xffff, e.y);
  }
}

// ---------------- GAT GEMM via 3-term bf16 MFMA; optional fused BN on input ----------------
template<bool BN_IN>
__global__ __launch_bounds__(256) void k_mm(const float* __restrict__ X,
    const short* __restrict__ W0, const short* __restrict__ W1, const short* __restrict__ W2,
    const float* __restrict__ att_s, const float* __restrict__ att_d,
    const float* __restrict__ bn,
    float* __restrict__ Y, float* __restrict__ a_src, float* __restrict__ a_dst, int n){
  const int wv = threadIdx.x >> 6, L = threadIdx.x & 63;
  const int quad = L >> 4, m = L & 15;
  const int row0 = blockIdx.x * 64 + wv * 16;
  const int lrow = min(row0 + m, n - 1);
  f4v acc[5];
  #pragma unroll
  for (int t = 0; t < 5; t++) acc[t] = (f4v){0.f,0.f,0.f,0.f};

  #pragma unroll
  for (int c = 0; c < 3; c++){
    float xv[8];
    if (c < 2){
      if (BN_IN){
        const float* hr = X + (size_t)lrow * D + c * 32 + quad * 8;
        #pragma unroll
        for (int j = 0; j < 8; j += 2){
          float2 hv = *(const float2*)(hr + j);
          int col = c * 32 + quad * 8 + j;
          xv[j]     = hv.x * bn[col]     + bn[D + col];
          xv[j + 1] = hv.y * bn[col + 1] + bn[D + col + 1];
        }
      } else {
        const float* xr = X + (size_t)lrow * SP;
        float4 p0 = *(const float4*)&xr[c * 32 + quad * 8];
        float4 p1 = *(const float4*)&xr[c * 32 + quad * 8 + 4];
        xv[0] = p0.x; xv[1] = p0.y; xv[2] = p0.z; xv[3] = p0.w;
        xv[4] = p1.x; xv[5] = p1.y; xv[6] = p1.z; xv[7] = p1.w;
      }
    } else {
      #pragma unroll
      for (int j = 0; j < 8; j++) xv[j] = 0.f;
      if (quad == 0){
        if (BN_IN){
          float2 hv = *(const float2*)(X + (size_t)lrow * D + 64);
          xv[0] = hv.x * bn[64] + bn[D + 64];
          xv[1] = hv.y * bn[65] + bn[D + 65];
        } else {
          float4 p0 = *(const float4*)&X[(size_t)lrow * SP + 64];
          xv[0] = p0.x; xv[1] = p0.y; xv[2] = p0.z; xv[3] = p0.w;
        }
      }
    }
    s8v a0, a1, a2;
    split8t(xv, a0, a1, a2);
    const short* b0p = W0 + (c * 5) * 512 + L * 8;
    const short* b1p = W1 + (c * 5) * 512 + L * 8;
    const short* b2p = W2 + (c * 5) * 512 + L * 8;
    #pragma unroll
    for (int t = 0; t < 5; t++){
      s8v b0v = *(const s8v*)(b0p + t * 512);
      s8v b1v = *(const s8v*)(b1p + t * 512);
      s8v b2v = *(const s8v*)(b2p + t * 512);
      MM6(acc[t], a0, a1, a2, b0v, b1v, b2v)
    }
  }

  float ps[4] = {0.f,0.f,0.f,0.f}, pd[4] = {0.f,0.f,0.f,0.f};
  #pragma unroll
  for (int t = 0; t < 5; t++){
    int col = t * 16 + m;
    float as_v = 0.f, ad_v = 0.f;
    if (col < D){ as_v = att_s[col]; ad_v = att_d[col]; }
    #pragma unroll
    for (int r = 0; r < 4; r++){
      ps[r] += acc[t][r] * as_v;
      pd[r] += acc[t][r] * ad_v;
    }
  }
  #pragma unroll
  for (int r = 0; r < 4; r++){
    int rw = row0 + quad * 4 + r;
    if (rw < n){
      float* yr = Y + (size_t)rw * SP;
      #pragma unroll
      for (int t = 0; t < 4; t++) yr[t * 16 + m] = acc[t][r];
      if (m < 4) yr[64 + m] = (m < 2) ? acc[4][r] : 0.f;
    }
  }
  #pragma unroll
  for (int o = 1; o <= 8; o <<= 1){
    #pragma unroll
    for (int r = 0; r < 4; r++){
      ps[r] += __shfl_xor(ps[r], o);
      pd[r] += __shfl_xor(pd[r], o);
    }
  }
  if (m == 0){
    #pragma unroll
    for (int r = 0; r < 4; r++){
      int rw = row0 + quad * 4 + r;
      if (rw < n){ a_src[rw] = ps[r]; a_dst[rw] = pd[r]; }
    }
  }
}

// ---------------- Fused 5-layer FC head: 32-row blocks, t-split across wave pairs ----------------
#define FST 84
__global__ __launch_bounds__(256) void k_fcmm(const float* __restrict__ X,
    const short* __restrict__ W0, const short* __restrict__ W1, const short* __restrict__ W2,
    const float* __restrict__ bpack, float* __restrict__ out, int n){
  __shared__ __align__(16) float xs[2][16][FST];
  const int wv = threadIdx.x >> 6, L = threadIdx.x & 63;
  const int quad = L >> 4, m = L & 15;
  const int rg = wv >> 1, th = wv & 1;
  const int row0 = blockIdx.x * 32 + rg * 16;
  const int lrow = min(row0 + m, n - 1);
  const float* xr = X + (size_t)lrow * SP;

  for (int l = 0; l < 5; l++){
    const int t0 = (l == 4) ? th : (th ? 3 : 0);
    const int nt = (l == 4) ? 1  : (th ? 2 : 3);
    f4v acc[3];
    #pragma unroll
    for (int t = 0; t < 3; t++) acc[t] = (f4v){0.f,0.f,0.f,0.f};
    #pragma unroll
    for (int c = 0; c < 3; c++){
      float xv[8];
      if (l == 0){
        if (c < 2){
          float4 p0 = *(const float4*)&xr[c * 32 + quad * 8];
          float4 p1 = *(const float4*)&xr[c * 32 + quad * 8 + 4];
          xv[0] = p0.x; xv[1] = p0.y; xv[2] = p0.z; xv[3] = p0.w;
          xv[4] = p1.x; xv[5] = p1.y; xv[6] = p1.z; xv[7] = p1.w;
        } else {
          float4 p0 = make_float4(0.f, 0.f, 0.f, 0.f);
          if (quad == 0) p0 = *(const float4*)&xr[64];
          xv[0] = p0.x; xv[1] = p0.y; xv[2] = p0.z; xv[3] = p0.w;
          xv[4] = 0.f; xv[5] = 0.f; xv[6] = 0.f; xv[7] = 0.f;
        }
      } else {
        if (c == 2 && quad >= 2){
          #pragma unroll
          for (int j = 0; j < 8; j++) xv[j] = 0.f;
        } else {
          float4 p0 = *(const float4*)&xs[rg][m][c * 32 + quad * 8];
          float4 p1 = *(const float4*)&xs[rg][m][c * 32 + quad * 8 + 4];
          xv[0] = p0.x; xv[1] = p0.y; xv[2] = p0.z; xv[3] = p0.w;
          xv[4] = p1.x; xv[5] = p1.y; xv[6] = p1.z; xv[7] = p1.w;
        }
      }
      s8v a0, a1, a2;
      split8t(xv, a0, a1, a2);
      const short* b0p = W0 + ((l * 3 + c) * 5 + t0) * 512 + L * 8;
      const short* b1p = W1 + ((l * 3 + c) * 5 + t0) * 512 + L * 8;
      const short* b2p = W2 + ((l * 3 + c) * 5 + t0) * 512 + L * 8;
      for (int t = 0; t < nt; t++){
        s8v b0v = *(const s8v*)(b0p + t * 512);
        s8v b1v = *(const s8v*)(b1p + t * 512);
        s8v b2v = *(const s8v*)(b2p + t * 512);
        MM6(acc[t], a0, a1, a2, b0v, b1v, b2v)
      }
    }
    if (l < 4){
      __syncthreads();
      for (int t = 0; t < nt; t++){
        int col = (t0 + t) * 16 + m;
        float bv = bpack[l * 80 + col];
        #pragma unroll
        for (int r = 0; r < 4; r++){
          float v = acc[t][r] + bv;
          xs[rg][quad * 4 + r][col] = v > 0.f ? v : 0.f;
        }
      }
      __syncthreads();
    } else {
      int col = t0 * 16 + m;
      #pragma unroll
      for (int r = 0; r < 4; r++){
        int rw = row0 + quad * 4 + r;
        if (col < 22 && rw < n) out[(size_t)rw * 22 + col] = acc[0][r] + bpack[4 * 80 + col];
      }
    }
  }
}

// ---------------- GAT softmax + aggregate: one wave per dst node, 8 edges/iter (proven round-9) ----------------
// All __shfl calls OUTSIDE divergent guards (ds_bpermute from inactive source lane is undefined).
__global__ __launch_bounds__(256) void k_agg(const float* __restrict__ y,
                                             const float* __restrict__ a_src, const float* __restrict__ a_dst,
                                             const int* __restrict__ rowptr, const int2* __restrict__ epair,
                                             const float* __restrict__ misc, int cidx,
                                             const float* __restrict__ bias,
                                             float* __restrict__ xout, int n){
  const int wid  = (int)((blockIdx.x * (size_t)blockDim.x + threadIdx.x) >> 6);
  const int lane = threadIdx.x & 63;
  if (wid >= n) return;
  const int beg = rowptr[wid];
  const int deg = rowptr[wid + 1] - beg;
  const float ce  = misc[2 * D + cidx];
  const float adn = a_dst[wid];
  const int g = lane >> 3, q = lane & 7;

  float4 accA = make_float4(0.f,0.f,0.f,0.f);
  float4 accB = make_float4(0.f,0.f,0.f,0.f);
  float2 tacc = make_float2(0.f,0.f);

  if (deg <= 64){
    int s = 0; float al = -INFINITY;
    bool act = lane < deg;
    if (act){
      int2 ep = epair[beg + lane];
      s = ep.x;
      al = lrelu(a_src[s] + adn + ce * __int_as_float(ep.y));
    }
    float mx = al;
    #pragma unroll
    for (int o = 32; o; o >>= 1) mx = fmaxf(mx, __shfl_xor(mx, o));
    float ex = act ? __expf(al - mx) : 0.f;
    float sum = ex;
    #pragma unroll
    for (int o = 32; o; o >>= 1) sum += __shfl_xor(sum, o);
    float coef = ex * (1.f / (sum + 1e-16f));
    for (int e0 = 0; e0 < deg; e0 += 8){
      int e = e0 + g;
      int   st = __shfl(s, e);
      float ct = __shfl(coef, e);
      if (e < deg){
        const float* row = y + (size_t)st * SP;
        float4 y0 = *(const float4*)&row[4 * q];
        float4 y1 = *(const float4*)&row[32 + 4 * q];
        fma4(accA, ct, y0);
        fma4(accB, ct, y1);
        if (q == 0){
          float2 tv = *(const float2*)&row[64];
          tacc.x += ct * tv.x; tacc.y += ct * tv.y;
        }
      }
    }
  } else {
    float mx = -INFINITY;
    for (int j0 = 0; j0 < deg; j0 += 64){
      int j = j0 + lane;
      if (j < deg){
        int2 ep = epair[beg + j];
        mx = fmaxf(mx, lrelu(a_src[ep.x] + adn + ce * __int_as_float(ep.y)));
      }
    }
    #pragma unroll
    for (int o = 32; o; o >>= 1) mx = fmaxf(mx, __shfl_xor(mx, o));
    float sum = 0.f;
    for (int j0 = 0; j0 < deg; j0 += 64){
      int j = j0 + lane;
      if (j < deg){
        int2 ep = epair[beg + j];
        sum += __expf(lrelu(a_src[ep.x] + adn + ce * __int_as_float(ep.y)) - mx);
      }
    }
    #pragma unroll
    for (int o = 32; o; o >>= 1) sum += __shfl_xor(sum, o);
    float inv = 1.f / (sum + 1e-16f);
    for (int j0 = 0; j0 < deg; j0 += 64){
      int cnt = min(64, deg - j0);
      int s = 0; float ex = 0.f;
      if (lane < cnt){
        int2 ep = epair[beg + j0 + lane];
        s = ep.x;
        ex = __expf(lrelu(a_src[s] + adn + ce * __int_as_float(ep.y)) - mx);
      }
      float coef = ex * inv;
      for (int e0 = 0; e0 < cnt; e0 += 8){
        int e = e0 + g;
        int   st = __shfl(s, e);
        float ct = __shfl(coef, e);
        if (e < cnt){
          const float* row = y + (size_t)st * SP;
          float4 y0 = *(const float4*)&row[4 * q];
          float4 y1 = *(const float4*)&row[32 + 4 * q];
          fma4(accA, ct, y0);
          fma4(accB, ct, y1);
          if (q == 0){
            float2 tv = *(const float2*)&row[64];
            tacc.x += ct * tv.x; tacc.y += ct * tv.y;
          }
        }
      }
    }
  }

  #pragma unroll
  for (int o = 8; o <= 32; o <<= 1){
    accA.x += __shfl_xor(accA.x, o); accA.y += __shfl_xor(accA.y, o);
    accA.z += __shfl_xor(accA.z, o); accA.w += __shfl_xor(accA.w, o);
    accB.x += __shfl_xor(accB.x, o); accB.y += __shfl_xor(accB.y, o);
    accB.z += __shfl_xor(accB.z, o); accB.w += __shfl_xor(accB.w, o);
    tacc.x += __shfl_xor(tacc.x, o); tacc.y += __shfl_xor(tacc.y, o);
  }
  float* orow = xout + (size_t)wid * SP;
  if (lane < 8){
    float4 v;
    v.x = accA.x + bias[4*lane+0]; v.x = v.x > 0.f ? v.x : 0.f;
    v.y = accA.y + bias[4*lane+1]; v.y = v.y > 0.f ? v.y : 0.f;
    v.z = accA.z + bias[4*lane+2]; v.z = v.z > 0.f ? v.z : 0.f;
    v.w = accA.w + bias[4*lane+3]; v.w = v.w > 0.f ? v.w : 0.f;
    *(float4*)&orow[4 * lane] = v;
  } else if (lane < 16){
    int qq = lane - 8;
    float4 v;
    v.x = accB.x + bias[32+4*qq+0]; v.x = v.x > 0.f ? v.x : 0.f;
    v.y = accB.y + bias[32+4*qq+1]; v.y = v.y > 0.f ? v.y : 0.f;
    v.z = accB.z + bias[32+4*qq+2]; v.z = v.z > 0.f ? v.z : 0.f;
    v.w = accB.w + bias[32+4*qq+3]; v.w = v.w > 0.f ? v.w : 0.f;
    *(float4*)&orow[32 + 4 * qq] = v;
  }
  if (lane == 0){
    float4 tv;
    tv.x = tacc.x + bias[64]; tv.x = tv.x > 0.f ? tv.x : 0.f;
    tv.y = tacc.y + bias[65]; tv.y = tv.y > 0.f ? tv.y : 0.f;
    tv.z = 0.f; tv.w = 0.f;
    *(float4*)&orow[64] = tv;
  }
}

// ---------------- launch ----------------
extern "C" void kernel_launch(void* const* d_in, const int* in_sizes, int n_in,
                              void* d_out, int out_size, void* d_ws, size_t ws_size,
                              hipStream_t stream){
  const float* h     = (const float*)d_in[0];
  const int*   ei    = (const int*)  d_in[1];
  const float* ew    = (const float*)d_in[2];
  const float* gamma = (const float*)d_in[3];
  const float* beta  = (const float*)d_in[4];
  const float *Wl[3], *bl[3], *asl[3], *adl[3], *Wel[3], *ael[3];
  int idx = 5;
  for (int l = 0; l < 3; l++){
    Wl[l]  = (const float*)d_in[idx++];
    bl[l]  = (const float*)d_in[idx++];
    asl[l] = (const float*)d_in[idx++];
    adl[l] = (const float*)d_in[idx++];
    Wel[l] = (const float*)d_in[idx++];
    ael[l] = (const float*)d_in[idx++];
  }
  const float *fw[5], *fb[5];
  for (int l = 0; l < 5; l++){ fw[l] = (const float*)d_in[idx++]; fb[l] = (const float*)d_in[idx++]; }

  int N = in_sizes[0] / D;
  int E = in_sizes[1] / 2;
  const int* src  = ei;
  const int* dstp = ei + E;

  char* base = (char*)d_ws;
  size_t o = 0;
  auto alloc = [&](size_t b){ size_t r = o; o += (b + 255) & ~(size_t)255; return r; };
  float*  bufA   = (float*)(base + alloc((size_t)N * SP * 4));
  float*  bufB   = (float*)(base + alloc((size_t)N * SP * 4));
  float*  a_src  = (float*)(base + alloc((size_t)N * 4));
  float*  a_dst  = (float*)(base + alloc((size_t)N * 4));
  float*  misc   = (float*)(base + alloc(512 * 4));
  float*  sums   = (float*)(base + alloc(2 * D * 4));
  int*    rowptr = (int*)  (base + alloc((size_t)(N + 1) * 4));
  int*    bhist  = (int*)  (base + alloc(256 * 4));
  int*    bbase  = (int*)  (base + alloc(257 * 4));
  int*    gcur   = (int*)  (base + alloc(256 * 4));
  int2*   epair  = (int2*) (base + alloc((size_t)E * 8));
  short*  W0p    = (short*)(base + alloc(3 * 7680 * 2));
  short*  W1p    = (short*)(base + alloc(3 * 7680 * 2));
  short*  W2p    = (short*)(base + alloc(3 * 7680 * 2));
  short*  FW0p   = (short*)(base + alloc(5 * 7680 * 2));
  short*  FW1p   = (short*)(base + alloc(5 * 7680 * 2));
  short*  FW2p   = (short*)(base + alloc(5 * 7680 * 2));
  float*  bpack  = (float*)(base + alloc(400 * 4));
  int2*   tmp    = (int2*)bufB;   // alias: bufB unused until first k_mm

  hipMemsetAsync(sums, 0, 2 * D * 4, stream);
  hipMemsetAsync(bhist, 0, 256 * 4, stream);

  k_stats_hist<<<512, 256, 0, stream>>>(h, dstp, sums, bhist, N, E);

  PrepArgs pa;
  pa.sums = sums; pa.gamma = gamma; pa.beta = beta;
  for (int l = 0; l < 3; l++){ pa.We[l] = Wel[l]; pa.ae[l] = ael[l]; pa.gw[l] = Wl[l]; }
  for (int l = 0; l < 5; l++){ pa.fw[l] = fw[l]; pa.fb[l] = fb[l]; }
  pa.misc = misc; pa.W0 = W0p; pa.W1 = W1p; pa.W2 = W2p;
  pa.F0 = FW0p; pa.F1 = FW1p; pa.F2 = FW2p; pa.bpack = bpack; pa.n = N;
  k_prep<<<34, 256, 0, stream>>>(pa);

  int NB = (N + 255) >> 8;
  k_bscan<<<1, 256, 0, stream>>>(bhist, bbase, gcur, rowptr, N, E);
  k_part<<<(E + PCHUNK - 1) / PCHUNK, 256, 0, stream>>>(src, dstp, ew, gcur, tmp, E);
  k_bsort<<<NB, 256, 0, stream>>>(tmp, bbase, epair, rowptr, N);

  int gb = (N + 63) / 64;
  int ab = (N + 3) / 4;

  k_mm<true ><<<gb, 256, 0, stream>>>(h,    W0p + 0 * 7680, W1p + 0 * 7680, W2p + 0 * 7680,
                                      asl[0], adl[0], misc, bufB, a_src, a_dst, N);
  k_agg<<<ab, 256, 0, stream>>>(bufB, a_src, a_dst, rowptr, epair, misc, 0, bl[0], bufA, N);
  k_mm<false><<<gb, 256, 0, stream>>>(bufA, W0p + 1 * 7680, W1p + 1 * 7680, W2p + 1 * 7680,
                                      asl[1], adl[1], misc, bufB, a_src, a_dst, N);
  k_agg<<<ab, 256, 0, stream>>>(bufB, a_src, a_dst, rowptr, epair, misc, 1, bl[1], bufA, N);
  k_mm<false><<<gb, 256, 0, stream>>>(bufA, W0p + 2 * 7680, W1p + 2 * 7680, W2p + 2 * 7680,
                                      asl[2], adl[2], misc, bufB, a_src, a_dst, N);
  k_agg<<<ab, 256, 0, stream>>>(bufB, a_src, a_dst, rowptr, epair, misc, 2, bl[2], bufA, N);

  int gb2 = (N + 31) / 32;
  k_fcmm<<<gb2, 256, 0, stream>>>(bufA, FW0p, FW1p, FW2p, bpack, (float*)d_out, N);
}

// Round 13
// 420.174 us; speedup vs baseline: 1.1596x; 1.0493x over previous
//
#include <hip/hip_runtime.h>
#include <math.h>

#define D 66
#define SP 68                 // padded fp32 row stride, 16B-aligned rows, cols 66,67 always 0
#define NEG_SLOPE 0.2f
#define CAP 6144

typedef short s8v __attribute__((ext_vector_type(8)));   // 8 bf16 bit-patterns = 4 VGPRs
typedef float f4v __attribute__((ext_vector_type(4)));

__device__ __forceinline__ float lrelu(float a){ return a > 0.f ? a : NEG_SLOPE * a; }
__device__ __forceinline__ void fma4(float4& a, float s, const float4& w){
  a.x = fmaf(s, w.x, a.x); a.y = fmaf(s, w.y, a.y);
  a.z = fmaf(s, w.z, a.z); a.w = fmaf(s, w.w, a.w);
}
__device__ __forceinline__ unsigned short bf16r(float f){   // RNE f32->bf16 (pack-time only)
  unsigned u = __float_as_uint(f);
  u += 0x7FFFu + ((u >> 16) & 1u);
  return (unsigned short)(u >> 16);
}
__device__ __forceinline__ float bf16f(unsigned short b){
  return __uint_as_float(((unsigned)b) << 16);
}
// 2-term truncation split: v = a0 + a1 + r, |r| <= 2^-16 |v| (each step exact)
__device__ __forceinline__ void split8d(const float* p, s8v& a0, s8v& a1){
  #pragma unroll
  for (int j = 0; j < 8; j++){
    float v = p[j];
    unsigned u0 = __float_as_uint(v) & 0xFFFF0000u;
    float r1 = v - __uint_as_float(u0);
    a0[j] = (short)(u0 >> 16);
    a1[j] = (short)(__float_as_uint(r1) >> 16);
  }
}
// 4-product accumulation: (a0+a1)(b0+b1); dropped terms ~2^-16 rel (activation trunc residual)
#define MM4(acc, a0, a1, b0v, b1v)                                         \
  acc = __builtin_amdgcn_mfma_f32_16x16x32_bf16(a0, b0v, acc, 0, 0, 0);    \
  acc = __builtin_amdgcn_mfma_f32_16x16x32_bf16(a1, b0v, acc, 0, 0, 0);    \
  acc = __builtin_amdgcn_mfma_f32_16x16x32_bf16(a0, b1v, acc, 0, 0, 0);    \
  acc = __builtin_amdgcn_mfma_f32_16x16x32_bf16(a1, b1v, acc, 0, 0, 0);

// ---------------- BN stats + bucket hist (merged) ----------------
__global__ __launch_bounds__(256) void k_stats_hist(const float* __restrict__ h, const int* __restrict__ dst,
                                                    float* __restrict__ sums, int* __restrict__ bhist,
                                                    int n, int E){
  int t = threadIdx.x;
  if (blockIdx.x < 256){
    __shared__ float ls[2 * D];
    if (t < 2 * D) ls[t] = 0.f;
    __syncthreads();
    int rpb = (n + 255) / 256;
    int r0 = blockIdx.x * rpb;
    int r1 = min(n, r0 + rpb);
    if (t < 3 * D){
      int c = t % D, seg = t / D;
      float s1 = 0.f, s2 = 0.f;
      for (int r = r0 + seg; r < r1; r += 3){
        float v = h[(size_t)r * D + c];
        s1 += v; s2 += v * v;
      }
      atomicAdd(&ls[c], s1);
      atomicAdd(&ls[D + c], s2);
    }
    __syncthreads();
    if (t < 2 * D) atomicAdd(&sums[t], ls[t]);
  } else {
    __shared__ int hh[256];
    hh[t] = 0;
    __syncthreads();
    int stride = 256 * 256;
    for (int e = (blockIdx.x - 256) * 256 + t; e < E; e += stride)
      atomicAdd(&hh[dst[e] >> 8], 1);
    __syncthreads();
    if (hh[t]) atomicAdd(&bhist[t], hh[t]);
  }
}

// ---------------- merged prep: BN finalize + GAT pack + FC pack (2-term RNE) ----------------
struct PrepArgs {
  const float *sums, *gamma, *beta;
  const float *We[3], *ae[3];
  const float *gw[3];
  const float *fw[5], *fb[5];
  float *misc; short *W0, *W1; short *F0, *F1; float *bpack;
  int n;
};

__global__ __launch_bounds__(256) void k_prep(PrepArgs pa){
  int t = threadIdx.x;
  if (blockIdx.x == 0){
    if (t < D){
      float mean = pa.sums[t] / (float)pa.n;
      float var  = pa.sums[D + t] / (float)pa.n - mean * mean;
      float inv  = rsqrtf(var + 1e-5f);
      float sc = pa.gamma[t] * inv;
      pa.misc[t] = sc;
      pa.misc[D + t] = pa.beta[t] - mean * sc;
    } else if (t >= D && t < D + 3){
      int l = t - D;
      float c = 0.f;
      for (int d = 0; d < D; d++) c += pa.We[l][d] * pa.ae[l][d];
      pa.misc[2 * D + l] = c;
    }
  } else if (blockIdx.x <= 12){
    int tid = (blockIdx.x - 1) * 256 + t;
    if (tid >= 3 * 960) return;
    int L = tid & 63;
    int ct = (tid >> 6) % 15;
    int lay = tid / 960;
    const float* w = pa.gw[lay];
    int c = ct / 5, tt = ct % 5;
    int nn = tt * 16 + (L & 15);
    int kb = c * 32 + (L >> 4) * 8;
    #pragma unroll
    for (int j = 0; j < 8; j++){
      int k = kb + j;
      float v = (k < D && nn < D) ? w[k * D + nn] : 0.f;
      unsigned short b0 = bf16r(v);
      float r1 = v - bf16f(b0);
      unsigned short b1 = bf16r(r1);
      pa.W0[tid * 8 + j] = (short)b0;
      pa.W1[tid * 8 + j] = (short)b1;
    }
  } else {
    int tid = (blockIdx.x - 13) * 256 + t;
    if (tid < 5 * 960){
      int L = tid & 63;
      int ct = (tid >> 6) % 15;
      int lay = tid / 960;
      const float* w = pa.fw[lay];
      int ncol = (lay == 4) ? 22 : D;
      int c = ct / 5, tt = ct % 5;
      int nn = tt * 16 + (L & 15);
      int kb = c * 32 + (L >> 4) * 8;
      #pragma unroll
      for (int j = 0; j < 8; j++){
        int k = kb + j;
        float v = (k < D && nn < ncol) ? w[k * ncol + nn] : 0.f;
        unsigned short b0 = bf16r(v);
        float r1 = v - bf16f(b0);
        unsigned short b1 = bf16r(r1);
        pa.F0[tid * 8 + j] = (short)b0;
        pa.F1[tid * 8 + j] = (short)b1;
      }
    } else if (tid < 5 * 960 + 400){
      int i = tid - 5 * 960;
      int lay = i / 80, col = i % 80;
      int ncol = (lay == 4) ? 22 : D;
      pa.bpack[i] = (col < ncol) ? pa.fb[lay][col] : 0.f;
    }
  }
}

// ---------------- CSR build: binned counting sort ----------------
__global__ void k_bscan(const int* __restrict__ bhist, int* __restrict__ bbase,
                        int* __restrict__ gcur, int* __restrict__ rowptr, int N, int E){
  __shared__ int sh[256];
  int t = threadIdx.x;
  int v = bhist[t];
  sh[t] = v; __syncthreads();
  for (int o = 1; o < 256; o <<= 1){
    int u = (t >= o) ? sh[t - o] : 0;
    __syncthreads();
    sh[t] += u;
    __syncthreads();
  }
  int ex = sh[t] - v;
  bbase[t] = ex;
  gcur[t] = ex;
  if (t == 255){ bbase[256] = sh[255]; rowptr[N] = E; }
}

#define PCHUNK 4096
__global__ __launch_bounds__(256) void k_part(const int* __restrict__ src, const int* __restrict__ dst,
                                              const float* __restrict__ ew,
                                              int* __restrict__ gcur, int2* __restrict__ tmp, int E){
  __shared__ int hist[256];
  __shared__ int base[256];
  int t = threadIdx.x;
  int e0 = blockIdx.x * PCHUNK;
  int eend = min(E, e0 + PCHUNK);
  hist[t] = 0;
  __syncthreads();
  for (int e = e0 + t; e < eend; e += 256)
    atomicAdd(&hist[dst[e] >> 8], 1);
  __syncthreads();
  if (hist[t] > 0) base[t] = atomicAdd(&gcur[t], hist[t]);
  hist[t] = 0;
  __syncthreads();
  for (int e = e0 + t; e < eend; e += 256){
    int d = dst[e];
    int b = d >> 8;
    int off = atomicAdd(&hist[b], 1);
    tmp[base[b] + off] = make_int2((src[e] & 0xffff) | ((d & 255) << 16), __float_as_int(ew[e]));
  }
}

__global__ __launch_bounds__(256) void k_bsort(const int2* __restrict__ tmp, const int* __restrict__ bbase,
                                               int2* __restrict__ epair, int* __restrict__ rowptr, int N){
  __shared__ int2 ebuf[CAP];
  __shared__ int lcnt[256];
  __shared__ int sc[256];
  __shared__ int lcur[256];
  int b = blockIdx.x, t = threadIdx.x;
  int s0 = bbase[b], s1 = bbase[b + 1];
  int cnt = s1 - s0;
  lcnt[t] = 0;
  __syncthreads();
  for (int j = t; j < cnt; j += 256){
    int2 e = tmp[s0 + j];
    if (j < CAP) ebuf[j] = e;
    atomicAdd(&lcnt[(e.x >> 16) & 255], 1);
  }
  __syncthreads();
  int v = lcnt[t];
  sc[t] = v; __syncthreads();
  for (int o = 1; o < 256; o <<= 1){
    int u = (t >= o) ? sc[t - o] : 0;
    __syncthreads();
    sc[t] += u;
    __syncthreads();
  }
  int ex = sc[t] - v;
  int node = (b << 8) + t;
  if (node < N) rowptr[node] = s0 + ex;
  lcur[t] = ex;
  __syncthreads();
  for (int j = t; j < cnt; j += 256){
    int2 e = (j < CAP) ? ebuf[j] : tmp[s0 + j];
    int i = (e.x >> 16) & 255;
    int p = atomicAdd(&lcur[i], 1);
    epair[s0 + p] = make_int2(e.x & 0xffff, e.y);
  }
}

// ---------------- GAT GEMM via 2-term bf16 MFMA; optional fused BN on input ----------------
template<bool BN_IN>
__global__ __launch_bounds__(256) void k_mm(const float* __restrict__ X,
    const short* __restrict__ W0, const short* __restrict__ W1,
    const float* __restrict__ att_s, const float* __restrict__ att_d,
    const float* __restrict__ bn,
    float* __restrict__ Y, float* __restrict__ a_src, float* __restrict__ a_dst, int n){
  const int wv = threadIdx.x >> 6, L = threadIdx.x & 63;
  const int quad = L >> 4, m = L & 15;
  const int row0 = blockIdx.x * 64 + wv * 16;
  const int lrow = min(row0 + m, n - 1);
  f4v acc[5];
  #pragma unroll
  for (int t = 0; t < 5; t++) acc[t] = (f4v){0.f,0.f,0.f,0.f};

  #pragma unroll
  for (int c = 0; c < 3; c++){
    float xv[8];
    if (c < 2){
      if (BN_IN){
        const float* hr = X + (size_t)lrow * D + c * 32 + quad * 8;
        #pragma unroll
        for (int j = 0; j < 8; j += 2){
          float2 hv = *(const float2*)(hr + j);
          int col = c * 32 + quad * 8 + j;
          xv[j]     = hv.x * bn[col]     + bn[D + col];
          xv[j + 1] = hv.y * bn[col + 1] + bn[D + col + 1];
        }
      } else {
        const float* xr = X + (size_t)lrow * SP;
        float4 p0 = *(const float4*)&xr[c * 32 + quad * 8];
        float4 p1 = *(const float4*)&xr[c * 32 + quad * 8 + 4];
        xv[0] = p0.x; xv[1] = p0.y; xv[2] = p0.z; xv[3] = p0.w;
        xv[4] = p1.x; xv[5] = p1.y; xv[6] = p1.z; xv[7] = p1.w;
      }
    } else {
      #pragma unroll
      for (int j = 0; j < 8; j++) xv[j] = 0.f;
      if (quad == 0){
        if (BN_IN){
          float2 hv = *(const float2*)(X + (size_t)lrow * D + 64);
          xv[0] = hv.x * bn[64] + bn[D + 64];
          xv[1] = hv.y * bn[65] + bn[D + 65];
        } else {
          float4 p0 = *(const float4*)&X[(size_t)lrow * SP + 64];
          xv[0] = p0.x; xv[1] = p0.y; xv[2] = p0.z; xv[3] = p0.w;
        }
      }
    }
    s8v a0, a1;
    split8d(xv, a0, a1);
    const short* b0p = W0 + (c * 5) * 512 + L * 8;
    const short* b1p = W1 + (c * 5) * 512 + L * 8;
    #pragma unroll
    for (int t = 0; t < 5; t++){
      s8v b0v = *(const s8v*)(b0p + t * 512);
      s8v b1v = *(const s8v*)(b1p + t * 512);
      MM4(acc[t], a0, a1, b0v, b1v)
    }
  }

  float ps[4] = {0.f,0.f,0.f,0.f}, pd[4] = {0.f,0.f,0.f,0.f};
  #pragma unroll
  for (int t = 0; t < 5; t++){
    int col = t * 16 + m;
    float as_v = 0.f, ad_v = 0.f;
    if (col < D){ as_v = att_s[col]; ad_v = att_d[col]; }
    #pragma unroll
    for (int r = 0; r < 4; r++){
      ps[r] += acc[t][r] * as_v;
      pd[r] += acc[t][r] * ad_v;
    }
  }
  #pragma unroll
  for (int r = 0; r < 4; r++){
    int rw = row0 + quad * 4 + r;
    if (rw < n){
      float* yr = Y + (size_t)rw * SP;
      #pragma unroll
      for (int t = 0; t < 4; t++) yr[t * 16 + m] = acc[t][r];
      if (m < 4) yr[64 + m] = (m < 2) ? acc[4][r] : 0.f;
    }
  }
  #pragma unroll
  for (int o = 1; o <= 8; o <<= 1){
    #pragma unroll
    for (int r = 0; r < 4; r++){
      ps[r] += __shfl_xor(ps[r], o);
      pd[r] += __shfl_xor(pd[r], o);
    }
  }
  if (m == 0){
    #pragma unroll
    for (int r = 0; r < 4; r++){
      int rw = row0 + quad * 4 + r;
      if (rw < n){ a_src[rw] = ps[r]; a_dst[rw] = pd[r]; }
    }
  }
}

// ---------------- Fused 5-layer FC head: 32-row blocks, t-split wave pairs, 2-term MFMA ----------------
#define FST 84
__global__ __launch_bounds__(256) void k_fcmm(const float* __restrict__ X,
    const short* __restrict__ W0, const short* __restrict__ W1,
    const float* __restrict__ bpack, float* __restrict__ out, int n){
  __shared__ __align__(16) float xs[2][16][FST];
  const int wv = threadIdx.x >> 6, L = threadIdx.x & 63;
  const int quad = L >> 4, m = L & 15;
  const int rg = wv >> 1, th = wv & 1;
  const int row0 = blockIdx.x * 32 + rg * 16;
  const int lrow = min(row0 + m, n - 1);
  const float* xr = X + (size_t)lrow * SP;

  for (int l = 0; l < 5; l++){
    const int t0 = (l == 4) ? th : (th ? 3 : 0);
    const int nt = (l == 4) ? 1  : (th ? 2 : 3);
    f4v acc[3];
    #pragma unroll
    for (int t = 0; t < 3; t++) acc[t] = (f4v){0.f,0.f,0.f,0.f};
    #pragma unroll
    for (int c = 0; c < 3; c++){
      float xv[8];
      if (l == 0){
        if (c < 2){
          float4 p0 = *(const float4*)&xr[c * 32 + quad * 8];
          float4 p1 = *(const float4*)&xr[c * 32 + quad * 8 + 4];
          xv[0] = p0.x; xv[1] = p0.y; xv[2] = p0.z; xv[3] = p0.w;
          xv[4] = p1.x; xv[5] = p1.y; xv[6] = p1.z; xv[7] = p1.w;
        } else {
          float4 p0 = make_float4(0.f, 0.f, 0.f, 0.f);
          if (quad == 0) p0 = *(const float4*)&xr[64];
          xv[0] = p0.x; xv[1] = p0.y; xv[2] = p0.z; xv[3] = p0.w;
          xv[4] = 0.f; xv[5] = 0.f; xv[6] = 0.f; xv[7] = 0.f;
        }
      } else {
        if (c == 2 && quad >= 2){
          #pragma unroll
          for (int j = 0; j < 8; j++) xv[j] = 0.f;
        } else {
          float4 p0 = *(const float4*)&xs[rg][m][c * 32 + quad * 8];
          float4 p1 = *(const float4*)&xs[rg][m][c * 32 + quad * 8 + 4];
          xv[0] = p0.x; xv[1] = p0.y; xv[2] = p0.z; xv[3] = p0.w;
          xv[4] = p1.x; xv[5] = p1.y; xv[6] = p1.z; xv[7] = p1.w;
        }
      }
      s8v a0, a1;
      split8d(xv, a0, a1);
      const short* b0p = W0 + ((l * 3 + c) * 5 + t0) * 512 + L * 8;
      const short* b1p = W1 + ((l * 3 + c) * 5 + t0) * 512 + L * 8;
      for (int t = 0; t < nt; t++){
        s8v b0v = *(const s8v*)(b0p + t * 512);
        s8v b1v = *(const s8v*)(b1p + t * 512);
        MM4(acc[t], a0, a1, b0v, b1v)
      }
    }
    if (l < 4){
      __syncthreads();
      for (int t = 0; t < nt; t++){
        int col = (t0 + t) * 16 + m;
        float bv = bpack[l * 80 + col];
        #pragma unroll
        for (int r = 0; r < 4; r++){
          float v = acc[t][r] + bv;
          xs[rg][quad * 4 + r][col] = v > 0.f ? v : 0.f;
        }
      }
      __syncthreads();
    } else {
      int col = t0 * 16 + m;
      #pragma unroll
      for (int r = 0; r < 4; r++){
        int rw = row0 + quad * 4 + r;
        if (col < 22 && rw < n) out[(size_t)rw * 22 + col] = acc[0][r] + bpack[4 * 80 + col];
      }
    }
  }
}

// ---------------- GAT softmax + aggregate: TWO nodes per wave (32 lanes each) ----------------
// All shfl_xor offsets <=16 stay within a 32-lane half; explicit-index shfls use (lane&32)|e.
// Loop bounds are wave-uniform (dmax) so every shfl source lane is active.
__global__ __launch_bounds__(256) void k_agg(const float* __restrict__ y,
                                             const float* __restrict__ a_src, const float* __restrict__ a_dst,
                                             const int* __restrict__ rowptr, const int2* __restrict__ epair,
                                             const float* __restrict__ misc, int cidx,
                                             const float* __restrict__ bias,
                                             float* __restrict__ xout, int n){
  const int wave = (int)((blockIdx.x * (size_t)blockDim.x + threadIdx.x) >> 6);
  const int lane = threadIdx.x & 63;
  const int half = lane >> 5, l32 = lane & 31;
  const int node = wave * 2 + half;
  const bool valid = node < n;
  const int nd = valid ? node : (n - 1);
  const int beg = rowptr[nd];
  const int deg = rowptr[nd + 1] - beg;
  const float ce  = misc[2 * D + cidx];
  const float adn = a_dst[nd];
  const int dmax = max(deg, __shfl_xor(deg, 32));

  float mx = -INFINITY, inv;
  int s = 0; float coef = 0.f;

  if (dmax <= 32){
    float al = -INFINITY;
    if (l32 < deg){
      int2 ep = epair[beg + l32];
      s = ep.x;
      al = lrelu(a_src[s] + adn + ce * __int_as_float(ep.y));
    }
    mx = al;
    #pragma unroll
    for (int o = 16; o; o >>= 1) mx = fmaxf(mx, __shfl_xor(mx, o));
    float ex = (l32 < deg) ? __expf(al - mx) : 0.f;
    float sum = ex;
    #pragma unroll
    for (int o = 16; o; o >>= 1) sum += __shfl_xor(sum, o);
    inv = 1.f / (sum + 1e-16f);
    coef = ex * inv;
  } else {
    for (int j0 = 0; j0 < dmax; j0 += 32){
      int j = j0 + l32;
      if (j < deg){
        int2 ep = epair[beg + j];
        mx = fmaxf(mx, lrelu(a_src[ep.x] + adn + ce * __int_as_float(ep.y)));
      }
    }
    #pragma unroll
    for (int o = 16; o; o >>= 1) mx = fmaxf(mx, __shfl_xor(mx, o));
    float sum = 0.f;
    for (int j0 = 0; j0 < dmax; j0 += 32){
      int j = j0 + l32;
      if (j < deg){
        int2 ep = epair[beg + j];
        sum += __expf(lrelu(a_src[ep.x] + adn + ce * __int_as_float(ep.y)) - mx);
      }
    }
    #pragma unroll
    for (int o = 16; o; o >>= 1) sum += __shfl_xor(sum, o);
    inv = 1.f / (sum + 1e-16f);
  }

  const int g = l32 >> 3, q = l32 & 7;   // 4 edge-groups x 8 lanes per node
  float4 accA = make_float4(0.f,0.f,0.f,0.f);
  float4 accB = make_float4(0.f,0.f,0.f,0.f);
  float2 tacc = make_float2(0.f,0.f);

  if (dmax <= 32){
    for (int e0 = 0; e0 < dmax; e0 += 4){
      int e = e0 + g;
      int   st = __shfl(s,    (lane & 32) | e);
      float ct = __shfl(coef, (lane & 32) | e);
      if (e < deg){
        const float* row = y + (size_t)st * SP;
        fma4(accA, ct, *(const float4*)&row[4 * q]);
        fma4(accB, ct, *(const float4*)&row[32 + 4 * q]);
        if (q == 0){
          float2 tv = *(const float2*)&row[64];
          tacc.x += ct * tv.x; tacc.y += ct * tv.y;
        }
      }
    }
  } else {
    for (int j0 = 0; j0 < dmax; j0 += 32){
      int cs = 0; float cc = 0.f;
      int j = j0 + l32;
      if (j < deg){
        int2 ep = epair[beg + j];
        cs = ep.x;
        cc = __expf(lrelu(a_src[cs] + adn + ce * __int_as_float(ep.y)) - mx) * inv;
      }
      int cmax = min(32, dmax - j0);
      for (int e0 = 0; e0 < cmax; e0 += 4){
        int e = e0 + g;
        int   st = __shfl(cs, (lane & 32) | e);
        float ct = __shfl(cc, (lane & 32) | e);
        if (j0 + e < deg){
          const float* row = y + (size_t)st * SP;
          fma4(accA, ct, *(const float4*)&row[4 * q]);
          fma4(accB, ct, *(const float4*)&row[32 + 4 * q]);
          if (q == 0){
            float2 tv = *(const float2*)&row[64];
            tacc.x += ct * tv.x; tacc.y += ct * tv.y;
          }
        }
      }
    }
  }

  // reduce over the 4 edge-groups (lane bits 3,4 within the half)
  #pragma unroll
  for (int o = 8; o <= 16; o <<= 1){
    accA.x += __shfl_xor(accA.x, o); accA.y += __shfl_xor(accA.y, o);
    accA.z += __shfl_xor(accA.z, o); accA.w += __shfl_xor(accA.w, o);
    accB.x += __shfl_xor(accB.x, o); accB.y += __shfl_xor(accB.y, o);
    accB.z += __shfl_xor(accB.z, o); accB.w += __shfl_xor(accB.w, o);
    tacc.x += __shfl_xor(tacc.x, o); tacc.y += __shfl_xor(tacc.y, o);
  }
  if (valid){
    float* orow = xout + (size_t)node * SP;
    if (l32 < 8){
      float4 v;
      v.x = accA.x + bias[4*l32+0]; v.x = v.x > 0.f ? v.x : 0.f;
      v.y = accA.y + bias[4*l32+1]; v.y = v.y > 0.f ? v.y : 0.f;
      v.z = accA.z + bias[4*l32+2]; v.z = v.z > 0.f ? v.z : 0.f;
      v.w = accA.w + bias[4*l32+3]; v.w = v.w > 0.f ? v.w : 0.f;
      *(float4*)&orow[4 * l32] = v;
    } else if (l32 < 16){
      int qq = l32 - 8;
      float4 v;
      v.x = accB.x + bias[32+4*qq+0]; v.x = v.x > 0.f ? v.x : 0.f;
      v.y = accB.y + bias[32+4*qq+1]; v.y = v.y > 0.f ? v.y : 0.f;
      v.z = accB.z + bias[32+4*qq+2]; v.z = v.z > 0.f ? v.z : 0.f;
      v.w = accB.w + bias[32+4*qq+3]; v.w = v.w > 0.f ? v.w : 0.f;
      *(float4*)&orow[32 + 4 * qq] = v;
    }
    if (l32 == 0){
      float4 tv;
      tv.x = tacc.x + bias[64]; tv.x = tv.x > 0.f ? tv.x : 0.f;
      tv.y = tacc.y + bias[65]; tv.y = tv.y > 0.f ? tv.y : 0.f;
      tv.z = 0.f; tv.w = 0.f;
      *(float4*)&orow[64] = tv;
    }
  }
}

// ---------------- launch ----------------
extern "C" void kernel_launch(void* const* d_in, const int* in_sizes, int n_in,
                              void* d_out, int out_size, void* d_ws, size_t ws_size,
                              hipStream_t stream){
  const float* h     = (const float*)d_in[0];
  const int*   ei    = (const int*)  d_in[1];
  const float* ew    = (const float*)d_in[2];
  const float* gamma = (const float*)d_in[3];
  const float* beta  = (const float*)d_in[4];
  const float *Wl[3], *bl[3], *asl[3], *adl[3], *Wel[3], *ael[3];
  int idx = 5;
  for (int l = 0; l < 3; l++){
    Wl[l]  = (const float*)d_in[idx++];
    bl[l]  = (const float*)d_in[idx++];
    asl[l] = (const float*)d_in[idx++];
    adl[l] = (const float*)d_in[idx++];
    Wel[l] = (const float*)d_in[idx++];
    ael[l] = (const float*)d_in[idx++];
  }
  const float *fw[5], *fb[5];
  for (int l = 0; l < 5; l++){ fw[l] = (const float*)d_in[idx++]; fb[l] = (const float*)d_in[idx++]; }

  int N = in_sizes[0] / D;
  int E = in_sizes[1] / 2;
  const int* src  = ei;
  const int* dstp = ei + E;

  char* base = (char*)d_ws;
  size_t o = 0;
  auto alloc = [&](size_t b){ size_t r = o; o += (b + 255) & ~(size_t)255; return r; };
  float*  bufA   = (float*)(base + alloc((size_t)N * SP * 4));
  float*  bufB   = (float*)(base + alloc((size_t)N * SP * 4));
  float*  a_src  = (float*)(base + alloc((size_t)N * 4));
  float*  a_dst  = (float*)(base + alloc((size_t)N * 4));
  float*  misc   = (float*)(base + alloc(512 * 4));
  float*  sums   = (float*)(base + alloc(2 * D * 4));
  int*    rowptr = (int*)  (base + alloc((size_t)(N + 1) * 4));
  int*    bhist  = (int*)  (base + alloc(256 * 4));
  int*    bbase  = (int*)  (base + alloc(257 * 4));
  int*    gcur   = (int*)  (base + alloc(256 * 4));
  int2*   epair  = (int2*) (base + alloc((size_t)E * 8));
  short*  W0p    = (short*)(base + alloc(3 * 7680 * 2));
  short*  W1p    = (short*)(base + alloc(3 * 7680 * 2));
  short*  FW0p   = (short*)(base + alloc(5 * 7680 * 2));
  short*  FW1p   = (short*)(base + alloc(5 * 7680 * 2));
  float*  bpack  = (float*)(base + alloc(400 * 4));
  int2*   tmp    = (int2*)bufB;   // alias: bufB unused until first k_mm

  hipMemsetAsync(sums, 0, 2 * D * 4, stream);
  hipMemsetAsync(bhist, 0, 256 * 4, stream);

  k_stats_hist<<<512, 256, 0, stream>>>(h, dstp, sums, bhist, N, E);

  PrepArgs pa;
  pa.sums = sums; pa.gamma = gamma; pa.beta = beta;
  for (int l = 0; l < 3; l++){ pa.We[l] = Wel[l]; pa.ae[l] = ael[l]; pa.gw[l] = Wl[l]; }
  for (int l = 0; l < 5; l++){ pa.fw[l] = fw[l]; pa.fb[l] = fb[l]; }
  pa.misc = misc; pa.W0 = W0p; pa.W1 = W1p;
  pa.F0 = FW0p; pa.F1 = FW1p; pa.bpack = bpack; pa.n = N;
  k_prep<<<34, 256, 0, stream>>>(pa);

  int NB = (N + 255) >> 8;
  k_bscan<<<1, 256, 0, stream>>>(bhist, bbase, gcur, rowptr, N, E);
  k_part<<<(E + PCHUNK - 1) / PCHUNK, 256, 0, stream>>>(src, dstp, ew, gcur, tmp, E);
  k_bsort<<<NB, 256, 0, stream>>>(tmp, bbase, epair, rowptr, N);

  int gb = (N + 63) / 64;
  int ab = (N + 7) / 8;   // 2 nodes per wave, 4 waves per block

  k_mm<true ><<<gb, 256, 0, stream>>>(h,    W0p + 0 * 7680, W1p + 0 * 7680,
                                      asl[0], adl[0], misc, bufB, a_src, a_dst, N);
  k_agg<<<ab, 256, 0, stream>>>(bufB, a_src, a_dst, rowptr, epair, misc, 0, bl[0], bufA, N);
  k_mm<false><<<gb, 256, 0, stream>>>(bufA, W0p + 1 * 7680, W1p + 1 * 7680,
                                      asl[1], adl[1], misc, bufB, a_src, a_dst, N);
  k_agg<<<ab, 256, 0, stream>>>(bufB, a_src, a_dst, rowptr, epair, misc, 1, bl[1], bufA, N);
  k_mm<false><<<gb, 256, 0, stream>>>(bufA, W0p + 2 * 7680, W1p + 2 * 7680,
                                      asl[2], adl[2], misc, bufB, a_src, a_dst, N);
  k_agg<<<ab, 256, 0, stream>>>(bufB, a_src, a_dst, rowptr, epair, misc, 2, bl[2], bufA, N);

  int gb2 = (N + 31) / 32;
  k_fcmm<<<gb2, 256, 0, stream>>>(bufA, FW0p, FW1p, bpack, (float*)d_out, N);
}

// Round 14
// 418.710 us; speedup vs baseline: 1.1637x; 1.0035x over previous
//
#include <hip/hip_runtime.h>
#include <math.h>

#define D 66
#define SP 68                 // padded fp32 row stride, 16B-aligned rows, cols 66,67 always 0
#define NEG_SLOPE 0.2f
#define CAP 6144

typedef short s8v __attribute__((ext_vector_type(8)));   // 8 bf16 bit-patterns = 4 VGPRs
typedef float f4v __attribute__((ext_vector_type(4)));

__device__ __forceinline__ float lrelu(float a){ return a > 0.f ? a : NEG_SLOPE * a; }
__device__ __forceinline__ void fma4(float4& a, float s, const float4& w){
  a.x = fmaf(s, w.x, a.x); a.y = fmaf(s, w.y, a.y);
  a.z = fmaf(s, w.z, a.z); a.w = fmaf(s, w.w, a.w);
}
__device__ __forceinline__ unsigned short bf16r(float f){   // RNE f32->bf16 (pack-time only)
  unsigned u = __float_as_uint(f);
  u += 0x7FFFu + ((u >> 16) & 1u);
  return (unsigned short)(u >> 16);
}
__device__ __forceinline__ float bf16f(unsigned short b){
  return __uint_as_float(((unsigned)b) << 16);
}
// 2-term truncation split: v = a0 + a1 + r, |r| <= 2^-16 |v| (each step exact)
__device__ __forceinline__ void split8d(const float* p, s8v& a0, s8v& a1){
  #pragma unroll
  for (int j = 0; j < 8; j++){
    float v = p[j];
    unsigned u0 = __float_as_uint(v) & 0xFFFF0000u;
    float r1 = v - __uint_as_float(u0);
    a0[j] = (short)(u0 >> 16);
    a1[j] = (short)(__float_as_uint(r1) >> 16);
  }
}
#define MM4(acc, a0, a1, b0v, b1v)                                         \
  acc = __builtin_amdgcn_mfma_f32_16x16x32_bf16(a0, b0v, acc, 0, 0, 0);    \
  acc = __builtin_amdgcn_mfma_f32_16x16x32_bf16(a1, b0v, acc, 0, 0, 0);    \
  acc = __builtin_amdgcn_mfma_f32_16x16x32_bf16(a0, b1v, acc, 0, 0, 0);    \
  acc = __builtin_amdgcn_mfma_f32_16x16x32_bf16(a1, b1v, acc, 0, 0, 0);

// ---------------- BN stats + bucket hist (merged) ----------------
__global__ __launch_bounds__(256) void k_stats_hist(const float* __restrict__ h, const int* __restrict__ dst,
                                                    float* __restrict__ sums, int* __restrict__ bhist,
                                                    int n, int E){
  int t = threadIdx.x;
  if (blockIdx.x < 256){
    __shared__ float ls[2 * D];
    if (t < 2 * D) ls[t] = 0.f;
    __syncthreads();
    int rpb = (n + 255) / 256;
    int r0 = blockIdx.x * rpb;
    int r1 = min(n, r0 + rpb);
    if (t < 3 * D){
      int c = t % D, seg = t / D;
      float s1 = 0.f, s2 = 0.f;
      for (int r = r0 + seg; r < r1; r += 3){
        float v = h[(size_t)r * D + c];
        s1 += v; s2 += v * v;
      }
      atomicAdd(&ls[c], s1);
      atomicAdd(&ls[D + c], s2);
    }
    __syncthreads();
    if (t < 2 * D) atomicAdd(&sums[t], ls[t]);
  } else {
    __shared__ int hh[256];
    hh[t] = 0;
    __syncthreads();
    int stride = 256 * 256;
    for (int e = (blockIdx.x - 256) * 256 + t; e < E; e += stride)
      atomicAdd(&hh[dst[e] >> 8], 1);
    __syncthreads();
    if (hh[t]) atomicAdd(&bhist[t], hh[t]);
  }
}

// ---------------- merged prep: BN finalize + GAT pack + FC pack (2-term RNE) ----------------
struct PrepArgs {
  const float *sums, *gamma, *beta;
  const float *We[3], *ae[3];
  const float *gw[3];
  const float *fw[5], *fb[5];
  float *misc; short *W0, *W1; short *F0, *F1; float *bpack;
  int n;
};

__global__ __launch_bounds__(256) void k_prep(PrepArgs pa){
  int t = threadIdx.x;
  if (blockIdx.x == 0){
    if (t < D){
      float mean = pa.sums[t] / (float)pa.n;
      float var  = pa.sums[D + t] / (float)pa.n - mean * mean;
      float inv  = rsqrtf(var + 1e-5f);
      float sc = pa.gamma[t] * inv;
      pa.misc[t] = sc;
      pa.misc[D + t] = pa.beta[t] - mean * sc;
    } else if (t >= D && t < D + 3){
      int l = t - D;
      float c = 0.f;
      for (int d = 0; d < D; d++) c += pa.We[l][d] * pa.ae[l][d];
      pa.misc[2 * D + l] = c;
    }
  } else if (blockIdx.x <= 12){
    int tid = (blockIdx.x - 1) * 256 + t;
    if (tid >= 3 * 960) return;
    int L = tid & 63;
    int ct = (tid >> 6) % 15;
    int lay = tid / 960;
    const float* w = pa.gw[lay];
    int c = ct / 5, tt = ct % 5;
    int nn = tt * 16 + (L & 15);
    int kb = c * 32 + (L >> 4) * 8;
    #pragma unroll
    for (int j = 0; j < 8; j++){
      int k = kb + j;
      float v = (k < D && nn < D) ? w[k * D + nn] : 0.f;
      unsigned short b0 = bf16r(v);
      float r1 = v - bf16f(b0);
      unsigned short b1 = bf16r(r1);
      pa.W0[tid * 8 + j] = (short)b0;
      pa.W1[tid * 8 + j] = (short)b1;
    }
  } else {
    int tid = (blockIdx.x - 13) * 256 + t;
    if (tid < 5 * 960){
      int L = tid & 63;
      int ct = (tid >> 6) % 15;
      int lay = tid / 960;
      const float* w = pa.fw[lay];
      int ncol = (lay == 4) ? 22 : D;
      int c = ct / 5, tt = ct % 5;
      int nn = tt * 16 + (L & 15);
      int kb = c * 32 + (L >> 4) * 8;
      #pragma unroll
      for (int j = 0; j < 8; j++){
        int k = kb + j;
        float v = (k < D && nn < ncol) ? w[k * ncol + nn] : 0.f;
        unsigned short b0 = bf16r(v);
        float r1 = v - bf16f(b0);
        unsigned short b1 = bf16r(r1);
        pa.F0[tid * 8 + j] = (short)b0;
        pa.F1[tid * 8 + j] = (short)b1;
      }
    } else if (tid < 5 * 960 + 400){
      int i = tid - 5 * 960;
      int lay = i / 80, col = i % 80;
      int ncol = (lay == 4) ? 22 : D;
      pa.bpack[i] = (col < ncol) ? pa.fb[lay][col] : 0.f;
    }
  }
}

// ---------------- CSR build: binned counting sort ----------------
__global__ void k_bscan(const int* __restrict__ bhist, int* __restrict__ bbase,
                        int* __restrict__ gcur, int* __restrict__ rowptr, int N, int E){
  __shared__ int sh[256];
  int t = threadIdx.x;
  int v = bhist[t];
  sh[t] = v; __syncthreads();
  for (int o = 1; o < 256; o <<= 1){
    int u = (t >= o) ? sh[t - o] : 0;
    __syncthreads();
    sh[t] += u;
    __syncthreads();
  }
  int ex = sh[t] - v;
  bbase[t] = ex;
  gcur[t] = ex;
  if (t == 255){ bbase[256] = sh[255]; rowptr[N] = E; }
}

#define PCHUNK 4096
__global__ __launch_bounds__(256) void k_part(const int* __restrict__ src, const int* __restrict__ dst,
                                              const float* __restrict__ ew,
                                              int* __restrict__ gcur, int2* __restrict__ tmp, int E){
  __shared__ int hist[256];
  __shared__ int base[256];
  int t = threadIdx.x;
  int e0 = blockIdx.x * PCHUNK;
  int eend = min(E, e0 + PCHUNK);
  hist[t] = 0;
  __syncthreads();
  for (int e = e0 + t; e < eend; e += 256)
    atomicAdd(&hist[dst[e] >> 8], 1);
  __syncthreads();
  if (hist[t] > 0) base[t] = atomicAdd(&gcur[t], hist[t]);
  hist[t] = 0;
  __syncthreads();
  for (int e = e0 + t; e < eend; e += 256){
    int d = dst[e];
    int b = d >> 8;
    int off = atomicAdd(&hist[b], 1);
    tmp[base[b] + off] = make_int2((src[e] & 0xffff) | ((d & 255) << 16), __float_as_int(ew[e]));
  }
}

__global__ __launch_bounds__(256) void k_bsort(const int2* __restrict__ tmp, const int* __restrict__ bbase,
                                               int2* __restrict__ epair, int* __restrict__ rowptr, int N){
  __shared__ int2 ebuf[CAP];
  __shared__ int lcnt[256];
  __shared__ int sc[256];
  __shared__ int lcur[256];
  int b = blockIdx.x, t = threadIdx.x;
  int s0 = bbase[b], s1 = bbase[b + 1];
  int cnt = s1 - s0;
  lcnt[t] = 0;
  __syncthreads();
  for (int j = t; j < cnt; j += 256){
    int2 e = tmp[s0 + j];
    if (j < CAP) ebuf[j] = e;
    atomicAdd(&lcnt[(e.x >> 16) & 255], 1);
  }
  __syncthreads();
  int v = lcnt[t];
  sc[t] = v; __syncthreads();
  for (int o = 1; o < 256; o <<= 1){
    int u = (t >= o) ? sc[t - o] : 0;
    __syncthreads();
    sc[t] += u;
    __syncthreads();
  }
  int ex = sc[t] - v;
  int node = (b << 8) + t;
  if (node < N) rowptr[node] = s0 + ex;
  lcur[t] = ex;
  __syncthreads();
  for (int j = t; j < cnt; j += 256){
    int2 e = (j < CAP) ? ebuf[j] : tmp[s0 + j];
    int i = (e.x >> 16) & 255;
    int p = atomicAdd(&lcur[i], 1);
    epair[s0 + p] = make_int2(e.x & 0xffff, e.y);
  }
}

// ---------------- GAT GEMM via 2-term bf16 MFMA; optional fused BN on input ----------------
template<bool BN_IN>
__global__ __launch_bounds__(256) void k_mm(const float* __restrict__ X,
    const short* __restrict__ W0, const short* __restrict__ W1,
    const float* __restrict__ att_s, const float* __restrict__ att_d,
    const float* __restrict__ bn,
    float* __restrict__ Y, float* __restrict__ a_src, float* __restrict__ a_dst, int n){
  const int wv = threadIdx.x >> 6, L = threadIdx.x & 63;
  const int quad = L >> 4, m = L & 15;
  const int row0 = blockIdx.x * 64 + wv * 16;
  const int lrow = min(row0 + m, n - 1);
  f4v acc[5];
  #pragma unroll
  for (int t = 0; t < 5; t++) acc[t] = (f4v){0.f,0.f,0.f,0.f};

  #pragma unroll
  for (int c = 0; c < 3; c++){
    float xv[8];
    if (c < 2){
      if (BN_IN){
        const float* hr = X + (size_t)lrow * D + c * 32 + quad * 8;
        #pragma unroll
        for (int j = 0; j < 8; j += 2){
          float2 hv = *(const float2*)(hr + j);
          int col = c * 32 + quad * 8 + j;
          xv[j]     = hv.x * bn[col]     + bn[D + col];
          xv[j + 1] = hv.y * bn[col + 1] + bn[D + col + 1];
        }
      } else {
        const float* xr = X + (size_t)lrow * SP;
        float4 p0 = *(const float4*)&xr[c * 32 + quad * 8];
        float4 p1 = *(const float4*)&xr[c * 32 + quad * 8 + 4];
        xv[0] = p0.x; xv[1] = p0.y; xv[2] = p0.z; xv[3] = p0.w;
        xv[4] = p1.x; xv[5] = p1.y; xv[6] = p1.z; xv[7] = p1.w;
      }
    } else {
      #pragma unroll
      for (int j = 0; j < 8; j++) xv[j] = 0.f;
      if (quad == 0){
        if (BN_IN){
          float2 hv = *(const float2*)(X + (size_t)lrow * D + 64);
          xv[0] = hv.x * bn[64] + bn[D + 64];
          xv[1] = hv.y * bn[65] + bn[D + 65];
        } else {
          float4 p0 = *(const float4*)&X[(size_t)lrow * SP + 64];
          xv[0] = p0.x; xv[1] = p0.y; xv[2] = p0.z; xv[3] = p0.w;
        }
      }
    }
    s8v a0, a1;
    split8d(xv, a0, a1);
    const short* b0p = W0 + (c * 5) * 512 + L * 8;
    const short* b1p = W1 + (c * 5) * 512 + L * 8;
    #pragma unroll
    for (int t = 0; t < 5; t++){
      s8v b0v = *(const s8v*)(b0p + t * 512);
      s8v b1v = *(const s8v*)(b1p + t * 512);
      MM4(acc[t], a0, a1, b0v, b1v)
    }
  }

  float ps[4] = {0.f,0.f,0.f,0.f}, pd[4] = {0.f,0.f,0.f,0.f};
  #pragma unroll
  for (int t = 0; t < 5; t++){
    int col = t * 16 + m;
    float as_v = 0.f, ad_v = 0.f;
    if (col < D){ as_v = att_s[col]; ad_v = att_d[col]; }
    #pragma unroll
    for (int r = 0; r < 4; r++){
      ps[r] += acc[t][r] * as_v;
      pd[r] += acc[t][r] * ad_v;
    }
  }
  #pragma unroll
  for (int r = 0; r < 4; r++){
    int rw = row0 + quad * 4 + r;
    if (rw < n){
      float* yr = Y + (size_t)rw * SP;
      #pragma unroll
      for (int t = 0; t < 4; t++) yr[t * 16 + m] = acc[t][r];
      if (m < 4) yr[64 + m] = (m < 2) ? acc[4][r] : 0.f;
    }
  }
  #pragma unroll
  for (int o = 1; o <= 8; o <<= 1){
    #pragma unroll
    for (int r = 0; r < 4; r++){
      ps[r] += __shfl_xor(ps[r], o);
      pd[r] += __shfl_xor(pd[r], o);
    }
  }
  if (m == 0){
    #pragma unroll
    for (int r = 0; r < 4; r++){
      int rw = row0 + quad * 4 + r;
      if (rw < n){ a_src[rw] = ps[r]; a_dst[rw] = pd[r]; }
    }
  }
}

// ---------------- Fused 5-layer FC head: 32-row blocks, t-split wave pairs, 2-term MFMA ----------------
#define FST 84
__global__ __launch_bounds__(256) void k_fcmm(const float* __restrict__ X,
    const short* __restrict__ W0, const short* __restrict__ W1,
    const float* __restrict__ bpack, float* __restrict__ out, int n){
  __shared__ __align__(16) float xs[2][16][FST];
  const int wv = threadIdx.x >> 6, L = threadIdx.x & 63;
  const int quad = L >> 4, m = L & 15;
  const int rg = wv >> 1, th = wv & 1;
  const int row0 = blockIdx.x * 32 + rg * 16;
  const int lrow = min(row0 + m, n - 1);
  const float* xr = X + (size_t)lrow * SP;

  for (int l = 0; l < 5; l++){
    const int t0 = (l == 4) ? th : (th ? 3 : 0);
    const int nt = (l == 4) ? 1  : (th ? 2 : 3);
    f4v acc[3];
    #pragma unroll
    for (int t = 0; t < 3; t++) acc[t] = (f4v){0.f,0.f,0.f,0.f};
    #pragma unroll
    for (int c = 0; c < 3; c++){
      float xv[8];
      if (l == 0){
        if (c < 2){
          float4 p0 = *(const float4*)&xr[c * 32 + quad * 8];
          float4 p1 = *(const float4*)&xr[c * 32 + quad * 8 + 4];
          xv[0] = p0.x; xv[1] = p0.y; xv[2] = p0.z; xv[3] = p0.w;
          xv[4] = p1.x; xv[5] = p1.y; xv[6] = p1.z; xv[7] = p1.w;
        } else {
          float4 p0 = make_float4(0.f, 0.f, 0.f, 0.f);
          if (quad == 0) p0 = *(const float4*)&xr[64];
          xv[0] = p0.x; xv[1] = p0.y; xv[2] = p0.z; xv[3] = p0.w;
          xv[4] = 0.f; xv[5] = 0.f; xv[6] = 0.f; xv[7] = 0.f;
        }
      } else {
        if (c == 2 && quad >= 2){
          #pragma unroll
          for (int j = 0; j < 8; j++) xv[j] = 0.f;
        } else {
          float4 p0 = *(const float4*)&xs[rg][m][c * 32 + quad * 8];
          float4 p1 = *(const float4*)&xs[rg][m][c * 32 + quad * 8 + 4];
          xv[0] = p0.x; xv[1] = p0.y; xv[2] = p0.z; xv[3] = p0.w;
          xv[4] = p1.x; xv[5] = p1.y; xv[6] = p1.z; xv[7] = p1.w;
        }
      }
      s8v a0, a1;
      split8d(xv, a0, a1);
      const short* b0p = W0 + ((l * 3 + c) * 5 + t0) * 512 + L * 8;
      const short* b1p = W1 + ((l * 3 + c) * 5 + t0) * 512 + L * 8;
      for (int t = 0; t < nt; t++){
        s8v b0v = *(const s8v*)(b0p + t * 512);
        s8v b1v = *(const s8v*)(b1p + t * 512);
        MM4(acc[t], a0, a1, b0v, b1v)
      }
    }
    if (l < 4){
      __syncthreads();
      for (int t = 0; t < nt; t++){
        int col = (t0 + t) * 16 + m;
        float bv = bpack[l * 80 + col];
        #pragma unroll
        for (int r = 0; r < 4; r++){
          float v = acc[t][r] + bv;
          xs[rg][quad * 4 + r][col] = v > 0.f ? v : 0.f;
        }
      }
      __syncthreads();
    } else {
      int col = t0 * 16 + m;
      #pragma unroll
      for (int r = 0; r < 4; r++){
        int rw = row0 + quad * 4 + r;
        if (col < 22 && rw < n) out[(size_t)rw * 22 + col] = acc[0][r] + bpack[4 * 80 + col];
      }
    }
  }
}

// ---------------- GAT softmax + aggregate: TWO nodes per wave, 8 edges in flight per node ----------------
// Phase 2: 8 edge-groups x 4 lanes per node-half. coef/src stay in registers from phase 1
// and are shfl-broadcast; all shfls outside divergent guards, wave-uniform loop bounds.
__global__ __launch_bounds__(256) void k_agg(const float* __restrict__ y,
                                             const float* __restrict__ a_src, const float* __restrict__ a_dst,
                                             const int* __restrict__ rowptr, const int2* __restrict__ epair,
                                             const float* __restrict__ misc, int cidx,
                                             const float* __restrict__ bias,
                                             float* __restrict__ xout, int n){
  const int wave = (int)((blockIdx.x * (size_t)blockDim.x + threadIdx.x) >> 6);
  const int lane = threadIdx.x & 63;
  const int half = lane >> 5, l32 = lane & 31;
  const int node = wave * 2 + half;
  const bool valid = node < n;
  const int nd = valid ? node : (n - 1);
  const int beg = rowptr[nd];
  const int deg = rowptr[nd + 1] - beg;
  const float ce  = misc[2 * D + cidx];
  const float adn = a_dst[nd];
  const int dmax = max(deg, __shfl_xor(deg, 32));

  float mx = -INFINITY, inv;
  int s = 0; float coef = 0.f;

  if (dmax <= 32){
    float al = -INFINITY;
    if (l32 < deg){
      int2 ep = epair[beg + l32];
      s = ep.x;
      al = lrelu(a_src[s] + adn + ce * __int_as_float(ep.y));
    }
    mx = al;
    #pragma unroll
    for (int o = 16; o; o >>= 1) mx = fmaxf(mx, __shfl_xor(mx, o));
    float ex = (l32 < deg) ? __expf(al - mx) : 0.f;
    float sum = ex;
    #pragma unroll
    for (int o = 16; o; o >>= 1) sum += __shfl_xor(sum, o);
    inv = 1.f / (sum + 1e-16f);
    coef = ex * inv;
  } else {
    for (int j0 = 0; j0 < dmax; j0 += 32){
      int j = j0 + l32;
      if (j < deg){
        int2 ep = epair[beg + j];
        mx = fmaxf(mx, lrelu(a_src[ep.x] + adn + ce * __int_as_float(ep.y)));
      }
    }
    #pragma unroll
    for (int o = 16; o; o >>= 1) mx = fmaxf(mx, __shfl_xor(mx, o));
    float sum = 0.f;
    for (int j0 = 0; j0 < dmax; j0 += 32){
      int j = j0 + l32;
      if (j < deg){
        int2 ep = epair[beg + j];
        sum += __expf(lrelu(a_src[ep.x] + adn + ce * __int_as_float(ep.y)) - mx);
      }
    }
    #pragma unroll
    for (int o = 16; o; o >>= 1) sum += __shfl_xor(sum, o);
    inv = 1.f / (sum + 1e-16f);
  }

  // phase 2: 8 edge-groups (g) x 4 lanes (q) per node-half -> 8 edges in flight
  const int g = l32 >> 2, q = l32 & 3;
  float4 acc0 = make_float4(0.f,0.f,0.f,0.f);   // cols  0+4q
  float4 acc1 = make_float4(0.f,0.f,0.f,0.f);   // cols 16+4q
  float4 acc2 = make_float4(0.f,0.f,0.f,0.f);   // cols 32+4q
  float4 acc3 = make_float4(0.f,0.f,0.f,0.f);   // cols 48+4q
  float2 tacc = make_float2(0.f,0.f);           // cols 64,65 (q==0)

  if (dmax <= 32){
    for (int e0 = 0; e0 < dmax; e0 += 8){
      int e = e0 + g;
      int   st = __shfl(s,    (lane & 32) | e);
      float ct = __shfl(coef, (lane & 32) | e);
      if (e < deg){
        const float* row = y + (size_t)st * SP;
        fma4(acc0, ct, *(const float4*)&row[      4 * q]);
        fma4(acc1, ct, *(const float4*)&row[16 + 4 * q]);
        fma4(acc2, ct, *(const float4*)&row[32 + 4 * q]);
        fma4(acc3, ct, *(const float4*)&row[48 + 4 * q]);
        if (q == 0){
          float2 tv = *(const float2*)&row[64];
          tacc.x += ct * tv.x; tacc.y += ct * tv.y;
        }
      }
    }
  } else {
    for (int j0 = 0; j0 < dmax; j0 += 32){
      int cs = 0; float cc = 0.f;
      int j = j0 + l32;
      if (j < deg){
        int2 ep = epair[beg + j];
        cs = ep.x;
        cc = __expf(lrelu(a_src[cs] + adn + ce * __int_as_float(ep.y)) - mx) * inv;
      }
      int cmax = min(32, dmax - j0);
      for (int e0 = 0; e0 < cmax; e0 += 8){
        int e = e0 + g;
        int   st = __shfl(cs, (lane & 32) | e);
        float ct = __shfl(cc, (lane & 32) | e);
        if (j0 + e < deg && e < cmax){
          const float* row = y + (size_t)st * SP;
          fma4(acc0, ct, *(const float4*)&row[      4 * q]);
          fma4(acc1, ct, *(const float4*)&row[16 + 4 * q]);
          fma4(acc2, ct, *(const float4*)&row[32 + 4 * q]);
          fma4(acc3, ct, *(const float4*)&row[48 + 4 * q]);
          if (q == 0){
            float2 tv = *(const float2*)&row[64];
            tacc.x += ct * tv.x; tacc.y += ct * tv.y;
          }
        }
      }
    }
  }

  // reduce over the 8 edge-groups (lane bits 2,3,4 within the half)
  #pragma unroll
  for (int o = 4; o <= 16; o <<= 1){
    acc0.x += __shfl_xor(acc0.x, o); acc0.y += __shfl_xor(acc0.y, o);
    acc0.z += __shfl_xor(acc0.z, o); acc0.w += __shfl_xor(acc0.w, o);
    acc1.x += __shfl_xor(acc1.x, o); acc1.y += __shfl_xor(acc1.y, o);
    acc1.z += __shfl_xor(acc1.z, o); acc1.w += __shfl_xor(acc1.w, o);
    acc2.x += __shfl_xor(acc2.x, o); acc2.y += __shfl_xor(acc2.y, o);
    acc2.z += __shfl_xor(acc2.z, o); acc2.w += __shfl_xor(acc2.w, o);
    acc3.x += __shfl_xor(acc3.x, o); acc3.y += __shfl_xor(acc3.y, o);
    acc3.z += __shfl_xor(acc3.z, o); acc3.w += __shfl_xor(acc3.w, o);
    tacc.x += __shfl_xor(tacc.x, o); tacc.y += __shfl_xor(tacc.y, o);
  }
  if (valid){
    float* orow = xout + (size_t)node * SP;
    if (l32 < 4){
      int c0 = 4 * l32;
      float4 v;
      v.x = acc0.x + bias[c0+0]; v.x = v.x > 0.f ? v.x : 0.f;
      v.y = acc0.y + bias[c0+1]; v.y = v.y > 0.f ? v.y : 0.f;
      v.z = acc0.z + bias[c0+2]; v.z = v.z > 0.f ? v.z : 0.f;
      v.w = acc0.w + bias[c0+3]; v.w = v.w > 0.f ? v.w : 0.f;
      *(float4*)&orow[c0] = v;
      v.x = acc1.x + bias[16+c0+0]; v.x = v.x > 0.f ? v.x : 0.f;
      v.y = acc1.y + bias[16+c0+1]; v.y = v.y > 0.f ? v.y : 0.f;
      v.z = acc1.z + bias[16+c0+2]; v.z = v.z > 0.f ? v.z : 0.f;
      v.w = acc1.w + bias[16+c0+3]; v.w = v.w > 0.f ? v.w : 0.f;
      *(float4*)&orow[16 + c0] = v;
      v.x = acc2.x + bias[32+c0+0]; v.x = v.x > 0.f ? v.x : 0.f;
      v.y = acc2.y + bias[32+c0+1]; v.y = v.y > 0.f ? v.y : 0.f;
      v.z = acc2.z + bias[32+c0+2]; v.z = v.z > 0.f ? v.z : 0.f;
      v.w = acc2.w + bias[32+c0+3]; v.w = v.w > 0.f ? v.w : 0.f;
      *(float4*)&orow[32 + c0] = v;
      v.x = acc3.x + bias[48+c0+0]; v.x = v.x > 0.f ? v.x : 0.f;
      v.y = acc3.y + bias[48+c0+1]; v.y = v.y > 0.f ? v.y : 0.f;
      v.z = acc3.z + bias[48+c0+2]; v.z = v.z > 0.f ? v.z : 0.f;
      v.w = acc3.w + bias[48+c0+3]; v.w = v.w > 0.f ? v.w : 0.f;
      *(float4*)&orow[48 + c0] = v;
    }
    if (l32 == 0){
      float4 tv;
      tv.x = tacc.x + bias[64]; tv.x = tv.x > 0.f ? tv.x : 0.f;
      tv.y = tacc.y + bias[65]; tv.y = tv.y > 0.f ? tv.y : 0.f;
      tv.z = 0.f; tv.w = 0.f;
      *(float4*)&orow[64] = tv;
    }
  }
}

// ---------------- launch ----------------
extern "C" void kernel_launch(void* const* d_in, const int* in_sizes, int n_in,
                              void* d_out, int out_size, void* d_ws, size_t ws_size,
                              hipStream_t stream){
  const float* h     = (const float*)d_in[0];
  const int*   ei    = (const int*)  d_in[1];
  const float* ew    = (const float*)d_in[2];
  const float* gamma = (const float*)d_in[3];
  const float* beta  = (const float*)d_in[4];
  const float *Wl[3], *bl[3], *asl[3], *adl[3], *Wel[3], *ael[3];
  int idx = 5;
  for (int l = 0; l < 3; l++){
    Wl[l]  = (const float*)d_in[idx++];
    bl[l]  = (const float*)d_in[idx++];
    asl[l] = (const float*)d_in[idx++];
    adl[l] = (const float*)d_in[idx++];
    Wel[l] = (const float*)d_in[idx++];
    ael[l] = (const float*)d_in[idx++];
  }
  const float *fw[5], *fb[5];
  for (int l = 0; l < 5; l++){ fw[l] = (const float*)d_in[idx++]; fb[l] = (const float*)d_in[idx++]; }

  int N = in_sizes[0] / D;
  int E = in_sizes[1] / 2;
  const int* src  = ei;
  const int* dstp = ei + E;

  char* base = (char*)d_ws;
  size_t o = 0;
  auto alloc = [&](size_t b){ size_t r = o; o += (b + 255) & ~(size_t)255; return r; };
  float*  bufA   = (float*)(base + alloc((size_t)N * SP * 4));
  float*  bufB   = (float*)(base + alloc((size_t)N * SP * 4));
  float*  a_src  = (float*)(base + alloc((size_t)N * 4));
  float*  a_dst  = (float*)(base + alloc((size_t)N * 4));
  float*  misc   = (float*)(base + alloc(512 * 4));
  float*  sums   = (float*)(base + alloc(2 * D * 4));
  int*    rowptr = (int*)  (base + alloc((size_t)(N + 1) * 4));
  int*    bhist  = (int*)  (base + alloc(256 * 4));
  int*    bbase  = (int*)  (base + alloc(257 * 4));
  int*    gcur   = (int*)  (base + alloc(256 * 4));
  int2*   epair  = (int2*) (base + alloc((size_t)E * 8));
  short*  W0p    = (short*)(base + alloc(3 * 7680 * 2));
  short*  W1p    = (short*)(base + alloc(3 * 7680 * 2));
  short*  FW0p   = (short*)(base + alloc(5 * 7680 * 2));
  short*  FW1p   = (short*)(base + alloc(5 * 7680 * 2));
  float*  bpack  = (float*)(base + alloc(400 * 4));
  int2*   tmp    = (int2*)bufB;   // alias: bufB unused until first k_mm

  hipMemsetAsync(sums, 0, 2 * D * 4, stream);
  hipMemsetAsync(bhist, 0, 256 * 4, stream);

  k_stats_hist<<<512, 256, 0, stream>>>(h, dstp, sums, bhist, N, E);

  PrepArgs pa;
  pa.sums = sums; pa.gamma = gamma; pa.beta = beta;
  for (int l = 0; l < 3; l++){ pa.We[l] = Wel[l]; pa.ae[l] = ael[l]; pa.gw[l] = Wl[l]; }
  for (int l = 0; l < 5; l++){ pa.fw[l] = fw[l]; pa.fb[l] = fb[l]; }
  pa.misc = misc; pa.W0 = W0p; pa.W1 = W1p;
  pa.F0 = FW0p; pa.F1 = FW1p; pa.bpack = bpack; pa.n = N;
  k_prep<<<34, 256, 0, stream>>>(pa);

  int NB = (N + 255) >> 8;
  k_bscan<<<1, 256, 0, stream>>>(bhist, bbase, gcur, rowptr, N, E);
  k_part<<<(E + PCHUNK - 1) / PCHUNK, 256, 0, stream>>>(src, dstp, ew, gcur, tmp, E);
  k_bsort<<<NB, 256, 0, stream>>>(tmp, bbase, epair, rowptr, N);

  int gb = (N + 63) / 64;
  int ab = (N + 7) / 8;   // 2 nodes per wave, 4 waves per block

  k_mm<true ><<<gb, 256, 0, stream>>>(h,    W0p + 0 * 7680, W1p + 0 * 7680,
                                      asl[0], adl[0], misc, bufB, a_src, a_dst, N);
  k_agg<<<ab, 256, 0, stream>>>(bufB, a_src, a_dst, rowptr, epair, misc, 0, bl[0], bufA, N);
  k_mm<false><<<gb, 256, 0, stream>>>(bufA, W0p + 1 * 7680, W1p + 1 * 7680,
                                      asl[1], adl[1], misc, bufB, a_src, a_dst, N);
  k_agg<<<ab, 256, 0, stream>>>(bufB, a_src, a_dst, rowptr, epair, misc, 1, bl[1], bufA, N);
  k_mm<false><<<gb, 256, 0, stream>>>(bufA, W0p + 2 * 7680, W1p + 2 * 7680,
                                      asl[2], adl[2], misc, bufB, a_src, a_dst, N);
  k_agg<<<ab, 256, 0, stream>>>(bufB, a_src, a_dst, rowptr, epair, misc, 2, bl[2], bufA, N);

  int gb2 = (N + 31) / 32;
  k_fcmm<<<gb2, 256, 0, stream>>>(bufA, FW0p, FW1p, bpack, (float*)d_out, N);
}